// Round 8
// baseline (260.428 us; speedup 1.0000x reference)
//
#include <hip/hip_runtime.h>
#include <hip/hip_bf16.h>
#include <cstdint>

#define B_DIM 8192
#define D_DIM 512
#define BM 128
#define BN 128
#define BK 32
#define KSTEPS (D_DIM / BK)   // 16
#define NCP 64                // col panels (slots in part[])

typedef __attribute__((ext_vector_type(8))) short bf16x8;
typedef __attribute__((ext_vector_type(4))) float f32x4;

typedef __attribute__((address_space(1))) const void* gas_ptr;
typedef __attribute__((address_space(3))) void* las_ptr;

static __device__ __forceinline__ unsigned short f2bf(float x) {
    __hip_bfloat16 h = __float2bfloat16(x);
    return *reinterpret_cast<unsigned short*>(&h);
}

// One wave per row: L2-normalize (f32) and emit bf16.
__global__ __launch_bounds__(256) void normalize_rows(
    const float* __restrict__ V, const float* __restrict__ T,
    unsigned short* __restrict__ Vn, unsigned short* __restrict__ Tn)
{
    const int wave = threadIdx.x >> 6;
    const int lane = threadIdx.x & 63;
    const int row = blockIdx.x * 4 + wave;     // 0..16383 (V rows then T rows)
    const float* src;
    unsigned short* dst;
    if (row < B_DIM) {
        src = V + (size_t)row * D_DIM;
        dst = Vn + (size_t)row * D_DIM;
    } else {
        src = T + (size_t)(row - B_DIM) * D_DIM;
        dst = Tn + (size_t)(row - B_DIM) * D_DIM;
    }
    float4 a = *(const float4*)(src + lane * 4);
    float4 b = *(const float4*)(src + 256 + lane * 4);
    float ss = a.x*a.x + a.y*a.y + a.z*a.z + a.w*a.w
             + b.x*b.x + b.y*b.y + b.z*b.z + b.w*b.w;
    #pragma unroll
    for (int off = 32; off; off >>= 1) ss += __shfl_xor(ss, off);
    const float inv = 1.0f / fmaxf(sqrtf(ss), 1e-12f);
    ushort4 oa, ob;
    oa.x = f2bf(a.x * inv); oa.y = f2bf(a.y * inv);
    oa.z = f2bf(a.z * inv); oa.w = f2bf(a.w * inv);
    ob.x = f2bf(b.x * inv); ob.y = f2bf(b.y * inv);
    ob.z = f2bf(b.z * inv); ob.w = f2bf(b.w * inv);
    *(ushort4*)(dst + lane * 4) = oa;
    *(ushort4*)(dst + 256 + lane * 4) = ob;
}

// mask[i][j] = noisy[i] | noisy[j] : only two row images exist.
// Pure linear stream: per wave-instruction 64 lanes x 16B = 1KB contiguous.
__global__ __launch_bounds__(256) void mask_fill(
    const int* __restrict__ noisy, float* __restrict__ mask_out)
{
    const int t = threadIdx.x;
    f32x4 ones;
    ones[0] = ones[1] = ones[2] = ones[3] = 1.0f;
    f32x4 pat[8];
    #pragma unroll
    for (int q = 0; q < 8; ++q) {
        const int4 nz = *(const int4*)&noisy[q * 1024 + t * 4];
        pat[q][0] = nz.x ? 1.0f : 0.0f;
        pat[q][1] = nz.y ? 1.0f : 0.0f;
        pat[q][2] = nz.z ? 1.0f : 0.0f;
        pat[q][3] = nz.w ? 1.0f : 0.0f;
    }
    const int row0 = blockIdx.x * 4;
    for (int r = 0; r < 4; ++r) {
        const int row = row0 + r;
        const int rn = noisy[row];          // uniform per block-row
        float* dst = mask_out + (size_t)row * B_DIM;
        if (rn) {
            #pragma unroll
            for (int q = 0; q < 8; ++q)
                *(f32x4*)(dst + q * 1024 + t * 4) = ones;
        } else {
            #pragma unroll
            for (int q = 0; q < 8; ++q)
                *(f32x4*)(dst + q * 1024 + t * 4) = pat[q];
        }
    }
}

// R7 structure, atomics removed: per-block row-sums are combined across the
// two wc-halves in LDS and written once per row to part[cp][row] (2MB ws).
// Every (cp,row) slot has exactly one writer: block (xcd,rp,cp) owns rows
// [brow, brow+128) and slot column cp.
__global__ __launch_bounds__(256, 4) void gemm_fused(
    const unsigned short* __restrict__ Vn, const unsigned short* __restrict__ Tn,
    const int* __restrict__ noisy,
    float* __restrict__ sim_out, float* __restrict__ part)
{
    // 32KB union: staging (2x8KB A + 2x8KB B) during K-loop;
    // lsum f32[2][128] then f32[64][128] sim restage during epilogue.
    __shared__ __align__(16) unsigned char smem[32768];
    unsigned short* Al = (unsigned short*)smem;            // [2][4096]
    unsigned short* Bl = (unsigned short*)(smem + 16384);  // [2][4096]

    const int tid  = threadIdx.x;
    const int wave = tid >> 6;
    const int lane = tid & 63;
    const int wr = wave >> 1;       // wave row (0..1)
    const int wc = wave & 1;        // wave col (0..1)

    // XCD-band mapping: xcd = bid&7 owns row band [xcd*8, xcd*8+8) panels;
    // column-panel-major within the band (proven FETCH win, R5: 77MB).
    const int bid = blockIdx.x;
    const int xcd = bid & 7;
    const int i   = bid >> 3;          // 0..511
    const int cp  = i >> 3;            // col panel 0..63 (slow)
    const int rp  = i & 7;             // row panel within band (fast)
    const int brow = (xcd * 8 + rp) * BM;
    const int bcol = cp * BN;

    const int sr = lane >> 2;          // staging row within 16-row chunk
    const int sc = (lane & 3) * 8;     // staging col (bf16 elements)
    const int c0 = wave * 2;

    const int fr = lane & 15;
    const int ko = (lane >> 4) * 8;

#define STAGE(buf, k0) do {                                                        \
        _Pragma("unroll")                                                          \
        for (int q = 0; q < 2; ++q) {                                              \
            const int cw  = c0 + q;                                                \
            const int row = cw * 16 + sr;                                          \
            const unsigned short* ga = Vn + (size_t)(brow + row) * D_DIM + (k0) + sc; \
            const unsigned short* gb = Tn + (size_t)(bcol + row) * D_DIM + (k0) + sc; \
            __builtin_amdgcn_global_load_lds((gas_ptr)ga, (las_ptr)&Al[(buf) * 4096 + cw * 512], 16, 0, 0); \
            __builtin_amdgcn_global_load_lds((gas_ptr)gb, (las_ptr)&Bl[(buf) * 4096 + cw * 512], 16, 0, 0); \
        }                                                                          \
    } while (0)

    f32x4 acc[4][4] = {};              // sim^T fragments

    STAGE(0, 0);
    __syncthreads();

    for (int t = 0; t < KSTEPS; ++t) {
        const int cur = t & 1;
        if (t < KSTEPS - 1)
            STAGE(cur ^ 1, (t + 1) * BK);   // prefetch next tile

        bf16x8 af[4], bfr[4];
        #pragma unroll
        for (int m = 0; m < 4; ++m)
            af[m] = *(const bf16x8*)&Al[cur * 4096 + (wr * 64 + m * 16 + fr) * BK + ko];
        #pragma unroll
        for (int n = 0; n < 4; ++n)
            bfr[n] = *(const bf16x8*)&Bl[cur * 4096 + (wc * 64 + n * 16 + fr) * BK + ko];

        // swapped operands: lane holds sim[m*16+(lane&15)][n*16+(lane>>4)*4+r]
        #pragma unroll
        for (int m = 0; m < 4; ++m)
            #pragma unroll
            for (int n = 0; n < 4; ++n)
                acc[m][n] = __builtin_amdgcn_mfma_f32_16x16x32_bf16(
                    bfr[n], af[m], acc[m][n], 0, 0, 0);

        __syncthreads();
    }
#undef STAGE

    const float Tinv = 1.0f / 0.07f;
    const int ci = lane & 15;           // sim row within 16-block
    const int cg = lane >> 4;           // sim col group (4 cols each)

    // ---- rowsum partials (registers -> LDS combine -> one store/row) ----
    int rn[4];
    #pragma unroll
    for (int m = 0; m < 4; ++m)
        rn[m] = noisy[brow + wr * 64 + m * 16 + ci];
    int4 cn4[4];
    #pragma unroll
    for (int n = 0; n < 4; ++n)
        cn4[n] = *(const int4*)&noisy[bcol + wc * 64 + n * 16 + cg * 4];

    float* lsum = (float*)smem;        // [2][128] (staging is dead now)
    #pragma unroll
    for (int m = 0; m < 4; ++m) {
        float partial = 0.0f;
        #pragma unroll
        for (int n = 0; n < 4; ++n) {
            const f32x4 s = acc[m][n];
            partial += (rn[m] | cn4[n].x) ? __expf(s[0] * Tinv) : 0.0f;
            partial += (rn[m] | cn4[n].y) ? __expf(s[1] * Tinv) : 0.0f;
            partial += (rn[m] | cn4[n].z) ? __expf(s[2] * Tinv) : 0.0f;
            partial += (rn[m] | cn4[n].w) ? __expf(s[3] * Tinv) : 0.0f;
        }
        partial += __shfl_xor(partial, 16);
        partial += __shfl_xor(partial, 32);
        if (lane < 16) lsum[wc * 128 + wr * 64 + m * 16 + ci] = partial;
    }
    __syncthreads();
    if (tid < 128)
        part[(size_t)cp * B_DIM + brow + tid] = lsum[tid] + lsum[128 + tid];

    // ---- sim stores: restage through LDS for row-contiguous segments ----
    // fbuf = f32[64][128], swizzle byte ^= (row&7)<<6 (2-way max both sides).
    const int l31  = tid & 31;
    const int rsub = tid >> 5;          // 0..7
    for (int h = 0; h < 2; ++h) {
        __syncthreads();                // lsum reads done / prev phase done
        if (wr == h) {
            #pragma unroll
            for (int m = 0; m < 4; ++m) {
                const int row = m * 16 + ci;            // 0..63
                #pragma unroll
                for (int n = 0; n < 4; ++n) {
                    const int col = wc * 64 + n * 16 + cg * 4;
                    int byte = (row * 128 + col) * 4;
                    byte ^= (row & 7) << 6;
                    *(f32x4*)(smem + byte) = acc[m][n];
                }
            }
        }
        __syncthreads();
        #pragma unroll
        for (int j = 0; j < 8; ++j) {
            const int row = j * 8 + rsub;               // 0..63
            int byte = (row * 128 + l31 * 4) * 4;
            byte ^= (row & 7) << 6;
            const f32x4 v = *(const f32x4*)(smem + byte);
            const int grow = brow + h * 64 + row;
            *(f32x4*)(sim_out + (size_t)grow * B_DIM + bcol + l31 * 4) = v;
        }
    }
}

// stage 1: 32 blocks x 256 rows -> per-block sum of log(rowsum+eps)
__global__ __launch_bounds__(256) void loss_stage1(
    const float* __restrict__ part, float* __restrict__ s1)
{
    __shared__ float wsum[4];
    const int row = blockIdx.x * 256 + threadIdx.x;
    float s = 0.0f;
    #pragma unroll
    for (int c = 0; c < NCP; ++c)
        s += part[(size_t)c * B_DIM + row];
    float l = logf(s + 1e-8f);
    #pragma unroll
    for (int off = 32; off; off >>= 1) l += __shfl_xor(l, off);
    if ((threadIdx.x & 63) == 0) wsum[threadIdx.x >> 6] = l;
    __syncthreads();
    if (threadIdx.x == 0)
        s1[blockIdx.x] = (wsum[0] + wsum[1]) + (wsum[2] + wsum[3]);
}

// stage 2: single wave sums the 32 block partials
__global__ __launch_bounds__(64) void loss_stage2(
    const float* __restrict__ s1, float* __restrict__ out)
{
    const int lane = threadIdx.x;
    float s = (lane < 32) ? s1[lane] : 0.0f;
    #pragma unroll
    for (int off = 32; off; off >>= 1) s += __shfl_xor(s, off);
    if (lane == 0) {
        const float loss = s * (1.0f / (float)B_DIM);
        out[0] = loss;   // complementary_loss
        out[1] = loss;   // brownian_loss (identical chain)
    }
}

extern "C" void kernel_launch(void* const* d_in, const int* in_sizes, int n_in,
                              void* d_out, int out_size, void* d_ws, size_t ws_size,
                              hipStream_t stream) {
    const float* V = (const float*)d_in[0];
    const float* T = (const float*)d_in[1];
    const int* noisy = (const int*)d_in[3];   // confident_clean_mask (d_in[2]) unused
    float* out = (float*)d_out;

    float* mask_out = out + 2;
    float* sim_out  = out + 2 + (size_t)B_DIM * B_DIM;

    unsigned short* Vn = (unsigned short*)d_ws;                       // 8 MB
    unsigned short* Tn = Vn + (size_t)B_DIM * D_DIM;                  // 8 MB
    float* part = (float*)(Tn + (size_t)B_DIM * D_DIM);               // 2 MB
    float* s1   = part + (size_t)NCP * B_DIM;                         // 128 B

    normalize_rows<<<(2 * B_DIM) / 4, 256, 0, stream>>>(V, T, Vn, Tn);
    mask_fill<<<B_DIM / 4, 256, 0, stream>>>(noisy, mask_out);
    gemm_fused<<<64 * 64, 256, 0, stream>>>(Vn, Tn, noisy, sim_out, part);
    loss_stage1<<<32, 256, 0, stream>>>(part, s1);
    loss_stage2<<<1, 64, 0, stream>>>(s1, out);
}

// Round 9
// 248.729 us; speedup vs baseline: 1.0470x; 1.0470x over previous
//
#include <hip/hip_runtime.h>
#include <hip/hip_bf16.h>
#include <cstdint>

#define B_DIM 8192
#define D_DIM 512
#define BM 128
#define BN 128
#define BK 32
#define KSTEPS (D_DIM / BK)   // 16
#define NCP 64                // col panels (slots in part[])

typedef __attribute__((ext_vector_type(8))) short bf16x8;
typedef __attribute__((ext_vector_type(4))) float f32x4;

typedef __attribute__((address_space(1))) const void* gas_ptr;
typedef __attribute__((address_space(3))) void* las_ptr;

static __device__ __forceinline__ unsigned short f2bf(float x) {
    __hip_bfloat16 h = __float2bfloat16(x);
    return *reinterpret_cast<unsigned short*>(&h);
}

// One wave per row: L2-normalize (f32) and emit bf16.
__global__ __launch_bounds__(256) void normalize_rows(
    const float* __restrict__ V, const float* __restrict__ T,
    unsigned short* __restrict__ Vn, unsigned short* __restrict__ Tn)
{
    const int wave = threadIdx.x >> 6;
    const int lane = threadIdx.x & 63;
    const int row = blockIdx.x * 4 + wave;     // 0..16383 (V rows then T rows)
    const float* src;
    unsigned short* dst;
    if (row < B_DIM) {
        src = V + (size_t)row * D_DIM;
        dst = Vn + (size_t)row * D_DIM;
    } else {
        src = T + (size_t)(row - B_DIM) * D_DIM;
        dst = Tn + (size_t)(row - B_DIM) * D_DIM;
    }
    float4 a = *(const float4*)(src + lane * 4);
    float4 b = *(const float4*)(src + 256 + lane * 4);
    float ss = a.x*a.x + a.y*a.y + a.z*a.z + a.w*a.w
             + b.x*b.x + b.y*b.y + b.z*b.z + b.w*b.w;
    #pragma unroll
    for (int off = 32; off; off >>= 1) ss += __shfl_xor(ss, off);
    const float inv = 1.0f / fmaxf(sqrtf(ss), 1e-12f);
    ushort4 oa, ob;
    oa.x = f2bf(a.x * inv); oa.y = f2bf(a.y * inv);
    oa.z = f2bf(a.z * inv); oa.w = f2bf(a.w * inv);
    ob.x = f2bf(b.x * inv); ob.y = f2bf(b.y * inv);
    ob.z = f2bf(b.z * inv); ob.w = f2bf(b.w * inv);
    *(ushort4*)(dst + lane * 4) = oa;
    *(ushort4*)(dst + 256 + lane * 4) = ob;
}

// mask[i][j] = noisy[i] | noisy[j] : only two row images exist.
// Pure linear stream: per wave-instruction 64 lanes x 16B = 1KB contiguous.
__global__ __launch_bounds__(256) void mask_fill(
    const int* __restrict__ noisy, float* __restrict__ mask_out)
{
    const int t = threadIdx.x;
    f32x4 ones;
    ones[0] = ones[1] = ones[2] = ones[3] = 1.0f;
    f32x4 pat[8];
    #pragma unroll
    for (int q = 0; q < 8; ++q) {
        const int4 nz = *(const int4*)&noisy[q * 1024 + t * 4];
        pat[q][0] = nz.x ? 1.0f : 0.0f;
        pat[q][1] = nz.y ? 1.0f : 0.0f;
        pat[q][2] = nz.z ? 1.0f : 0.0f;
        pat[q][3] = nz.w ? 1.0f : 0.0f;
    }
    const int row0 = blockIdx.x * 4;
    for (int r = 0; r < 4; ++r) {
        const int row = row0 + r;
        const int rn = noisy[row];          // uniform per block-row
        float* dst = mask_out + (size_t)row * B_DIM;
        if (rn) {
            #pragma unroll
            for (int q = 0; q < 8; ++q)
                *(f32x4*)(dst + q * 1024 + t * 4) = ones;
        } else {
            #pragma unroll
            for (int q = 0; q < 8; ++q)
                *(f32x4*)(dst + q * 1024 + t * 4) = pat[q];
        }
    }
}

// R8 structure + T4 counted-vmcnt pipeline: 3 staging buffers, stage 2 tiles
// ahead, per-step s_waitcnt vmcnt(4) + raw s_barrier (NEVER vmcnt(0) in the
// main loop). Hazard audit: buf[(t+2)%3]'s previous readers (iter t-1)
// completed their ds_reads before MFMA(t-1) (lgkmcnt), which precedes
// barrier(t); STAGE(t+2) issues after barrier(t). Epilogue smem reuse is
// fenced by __syncthreads() after the loop.
__global__ __launch_bounds__(256, 3) void gemm_fused(
    const unsigned short* __restrict__ Vn, const unsigned short* __restrict__ Tn,
    const int* __restrict__ noisy,
    float* __restrict__ sim_out, float* __restrict__ part)
{
    // 48KB: 3 x (8KB A + 8KB B) staging; epilogue reuses first 32KB.
    __shared__ __align__(16) unsigned char smem[49152];

    const int tid  = threadIdx.x;
    const int wave = tid >> 6;
    const int lane = tid & 63;
    const int wr = wave >> 1;       // wave row (0..1)
    const int wc = wave & 1;        // wave col (0..1)

    // XCD-band mapping: xcd = bid&7 owns row band [xcd*8, xcd*8+8) panels;
    // column-panel-major within the band (proven FETCH win, R5: 77MB).
    const int bid = blockIdx.x;
    const int xcd = bid & 7;
    const int i   = bid >> 3;          // 0..511
    const int cp  = i >> 3;            // col panel 0..63 (slow)
    const int rp  = i & 7;             // row panel within band (fast)
    const int brow = (xcd * 8 + rp) * BM;
    const int bcol = cp * BN;

    const int sr = lane >> 2;          // staging row within 16-row chunk
    const int sc = (lane & 3) * 8;     // staging col (bf16 elements)
    const int c0 = wave * 2;

    const int fr = lane & 15;
    const int ko = (lane >> 4) * 8;

    // buf base (bytes): A at buf*16384, B at buf*16384 + 8192
#define STAGE(buf, k0) do {                                                        \
        _Pragma("unroll")                                                          \
        for (int q = 0; q < 2; ++q) {                                              \
            const int cw  = c0 + q;                                                \
            const int row = cw * 16 + sr;                                          \
            const unsigned short* ga = Vn + (size_t)(brow + row) * D_DIM + (k0) + sc; \
            const unsigned short* gb = Tn + (size_t)(bcol + row) * D_DIM + (k0) + sc; \
            __builtin_amdgcn_global_load_lds((gas_ptr)ga, (las_ptr)(smem + (buf) * 16384 + cw * 1024), 16, 0, 0); \
            __builtin_amdgcn_global_load_lds((gas_ptr)gb, (las_ptr)(smem + (buf) * 16384 + 8192 + cw * 1024), 16, 0, 0); \
        }                                                                          \
    } while (0)

    f32x4 acc[4][4] = {};              // sim^T fragments

    STAGE(0, 0);                       // 4 loads/wave in flight
    STAGE(1, BK);                      // 8 loads/wave in flight

    #pragma unroll
    for (int t = 0; t < KSTEPS; ++t) {
        const int cur = t % 3;
        // wait for tile t's 4 loads (tile t+1's 4 remain in flight);
        // only the last step drains fully.
        if (t < KSTEPS - 1) { asm volatile("s_waitcnt vmcnt(4)" ::: "memory"); }
        else                { asm volatile("s_waitcnt vmcnt(0)" ::: "memory"); }
        __builtin_amdgcn_sched_barrier(0);
        __builtin_amdgcn_s_barrier();      // all waves: tile t fully in LDS
        __builtin_amdgcn_sched_barrier(0);

        if (t + 2 < KSTEPS)
            STAGE((t + 2) % 3, (t + 2) * BK);   // refill; stays in flight
                                                // across the next barrier

        const unsigned short* Ab = (const unsigned short*)(smem + cur * 16384);
        const unsigned short* Bb = (const unsigned short*)(smem + cur * 16384 + 8192);
        bf16x8 af[4], bfr[4];
        #pragma unroll
        for (int m = 0; m < 4; ++m)
            af[m] = *(const bf16x8*)&Ab[(wr * 64 + m * 16 + fr) * BK + ko];
        #pragma unroll
        for (int n = 0; n < 4; ++n)
            bfr[n] = *(const bf16x8*)&Bb[(wc * 64 + n * 16 + fr) * BK + ko];

        // swapped operands: lane holds sim[m*16+(lane&15)][n*16+(lane>>4)*4+r]
        #pragma unroll
        for (int m = 0; m < 4; ++m)
            #pragma unroll
            for (int n = 0; n < 4; ++n)
                acc[m][n] = __builtin_amdgcn_mfma_f32_16x16x32_bf16(
                    bfr[n], af[m], acc[m][n], 0, 0, 0);
    }
#undef STAGE

    __syncthreads();   // all waves done reading staging bufs; smem reusable

    const float Tinv = 1.0f / 0.07f;
    const int ci = lane & 15;           // sim row within 16-block
    const int cg = lane >> 4;           // sim col group (4 cols each)

    // ---- rowsum partials (registers -> LDS combine -> one store/row) ----
    int rn[4];
    #pragma unroll
    for (int m = 0; m < 4; ++m)
        rn[m] = noisy[brow + wr * 64 + m * 16 + ci];
    int4 cn4[4];
    #pragma unroll
    for (int n = 0; n < 4; ++n)
        cn4[n] = *(const int4*)&noisy[bcol + wc * 64 + n * 16 + cg * 4];

    float* lsum = (float*)smem;        // [2][128]
    #pragma unroll
    for (int m = 0; m < 4; ++m) {
        float partial = 0.0f;
        #pragma unroll
        for (int n = 0; n < 4; ++n) {
            const f32x4 s = acc[m][n];
            partial += (rn[m] | cn4[n].x) ? __expf(s[0] * Tinv) : 0.0f;
            partial += (rn[m] | cn4[n].y) ? __expf(s[1] * Tinv) : 0.0f;
            partial += (rn[m] | cn4[n].z) ? __expf(s[2] * Tinv) : 0.0f;
            partial += (rn[m] | cn4[n].w) ? __expf(s[3] * Tinv) : 0.0f;
        }
        partial += __shfl_xor(partial, 16);
        partial += __shfl_xor(partial, 32);
        if (lane < 16) lsum[wc * 128 + wr * 64 + m * 16 + ci] = partial;
    }
    __syncthreads();
    if (tid < 128)
        part[(size_t)cp * B_DIM + brow + tid] = lsum[tid] + lsum[128 + tid];

    // ---- sim stores: restage through LDS for row-contiguous segments ----
    // fbuf = f32[64][128], swizzle byte ^= (row&7)<<6 (2-way max both sides).
    const int l31  = tid & 31;
    const int rsub = tid >> 5;          // 0..7
    for (int h = 0; h < 2; ++h) {
        __syncthreads();                // lsum reads done / prev phase done
        if (wr == h) {
            #pragma unroll
            for (int m = 0; m < 4; ++m) {
                const int row = m * 16 + ci;            // 0..63
                #pragma unroll
                for (int n = 0; n < 4; ++n) {
                    const int col = wc * 64 + n * 16 + cg * 4;
                    int byte = (row * 128 + col) * 4;
                    byte ^= (row & 7) << 6;
                    *(f32x4*)(smem + byte) = acc[m][n];
                }
            }
        }
        __syncthreads();
        #pragma unroll
        for (int j = 0; j < 8; ++j) {
            const int row = j * 8 + rsub;               // 0..63
            int byte = (row * 128 + l31 * 4) * 4;
            byte ^= (row & 7) << 6;
            const f32x4 v = *(const f32x4*)(smem + byte);
            const int grow = brow + h * 64 + row;
            *(f32x4*)(sim_out + (size_t)grow * B_DIM + bcol + l31 * 4) = v;
        }
    }
}

// stage 1: 32 blocks x 256 rows -> per-block sum of log(rowsum+eps)
__global__ __launch_bounds__(256) void loss_stage1(
    const float* __restrict__ part, float* __restrict__ s1)
{
    __shared__ float wsum[4];
    const int row = blockIdx.x * 256 + threadIdx.x;
    float s = 0.0f;
    #pragma unroll
    for (int c = 0; c < NCP; ++c)
        s += part[(size_t)c * B_DIM + row];
    float l = logf(s + 1e-8f);
    #pragma unroll
    for (int off = 32; off; off >>= 1) l += __shfl_xor(l, off);
    if ((threadIdx.x & 63) == 0) wsum[threadIdx.x >> 6] = l;
    __syncthreads();
    if (threadIdx.x == 0)
        s1[blockIdx.x] = (wsum[0] + wsum[1]) + (wsum[2] + wsum[3]);
}

// stage 2: single wave sums the 32 block partials
__global__ __launch_bounds__(64) void loss_stage2(
    const float* __restrict__ s1, float* __restrict__ out)
{
    const int lane = threadIdx.x;
    float s = (lane < 32) ? s1[lane] : 0.0f;
    #pragma unroll
    for (int off = 32; off; off >>= 1) s += __shfl_xor(s, off);
    if (lane == 0) {
        const float loss = s * (1.0f / (float)B_DIM);
        out[0] = loss;   // complementary_loss
        out[1] = loss;   // brownian_loss (identical chain)
    }
}

extern "C" void kernel_launch(void* const* d_in, const int* in_sizes, int n_in,
                              void* d_out, int out_size, void* d_ws, size_t ws_size,
                              hipStream_t stream) {
    const float* V = (const float*)d_in[0];
    const float* T = (const float*)d_in[1];
    const int* noisy = (const int*)d_in[3];   // confident_clean_mask (d_in[2]) unused
    float* out = (float*)d_out;

    float* mask_out = out + 2;
    float* sim_out  = out + 2 + (size_t)B_DIM * B_DIM;

    unsigned short* Vn = (unsigned short*)d_ws;                       // 8 MB
    unsigned short* Tn = Vn + (size_t)B_DIM * D_DIM;                  // 8 MB
    float* part = (float*)(Tn + (size_t)B_DIM * D_DIM);               // 2 MB
    float* s1   = part + (size_t)NCP * B_DIM;                         // 128 B

    normalize_rows<<<(2 * B_DIM) / 4, 256, 0, stream>>>(V, T, Vn, Tn);
    mask_fill<<<B_DIM / 4, 256, 0, stream>>>(noisy, mask_out);
    gemm_fused<<<64 * 64, 256, 0, stream>>>(Vn, Tn, noisy, sim_out, part);
    loss_stage1<<<32, 256, 0, stream>>>(part, s1);
    loss_stage2<<<1, 64, 0, stream>>>(s1, out);
}

// Round 10
// 247.705 us; speedup vs baseline: 1.0514x; 1.0041x over previous
//
#include <hip/hip_runtime.h>
#include <hip/hip_bf16.h>
#include <cstdint>

#define B_DIM 8192
#define D_DIM 512
#define BM 128
#define BN 128
#define BK 32
#define KSTEPS (D_DIM / BK)   // 16
#define NCP 64                // col panels (slots in part[])

typedef __attribute__((ext_vector_type(8))) short bf16x8;
typedef __attribute__((ext_vector_type(4))) float f32x4;

typedef __attribute__((address_space(1))) const void* gas_ptr;
typedef __attribute__((address_space(3))) void* las_ptr;

static __device__ __forceinline__ unsigned short f2bf(float x) {
    __hip_bfloat16 h = __float2bfloat16(x);
    return *reinterpret_cast<unsigned short*>(&h);
}

// One wave per row: L2-normalize (f32) and emit bf16.
__global__ __launch_bounds__(256) void normalize_rows(
    const float* __restrict__ V, const float* __restrict__ T,
    unsigned short* __restrict__ Vn, unsigned short* __restrict__ Tn)
{
    const int wave = threadIdx.x >> 6;
    const int lane = threadIdx.x & 63;
    const int row = blockIdx.x * 4 + wave;     // 0..16383 (V rows then T rows)
    const float* src;
    unsigned short* dst;
    if (row < B_DIM) {
        src = V + (size_t)row * D_DIM;
        dst = Vn + (size_t)row * D_DIM;
    } else {
        src = T + (size_t)(row - B_DIM) * D_DIM;
        dst = Tn + (size_t)(row - B_DIM) * D_DIM;
    }
    float4 a = *(const float4*)(src + lane * 4);
    float4 b = *(const float4*)(src + 256 + lane * 4);
    float ss = a.x*a.x + a.y*a.y + a.z*a.z + a.w*a.w
             + b.x*b.x + b.y*b.y + b.z*b.z + b.w*b.w;
    #pragma unroll
    for (int off = 32; off; off >>= 1) ss += __shfl_xor(ss, off);
    const float inv = 1.0f / fmaxf(sqrtf(ss), 1e-12f);
    ushort4 oa, ob;
    oa.x = f2bf(a.x * inv); oa.y = f2bf(a.y * inv);
    oa.z = f2bf(a.z * inv); oa.w = f2bf(a.w * inv);
    ob.x = f2bf(b.x * inv); ob.y = f2bf(b.y * inv);
    ob.z = f2bf(b.z * inv); ob.w = f2bf(b.w * inv);
    *(ushort4*)(dst + lane * 4) = oa;
    *(ushort4*)(dst + 256 + lane * 4) = ob;
}

// mask[i][j] = noisy[i] | noisy[j] : only two row images exist.
// Pure linear stream: per wave-instruction 64 lanes x 16B = 1KB contiguous.
__global__ __launch_bounds__(256) void mask_fill(
    const int* __restrict__ noisy, float* __restrict__ mask_out)
{
    const int t = threadIdx.x;
    f32x4 ones;
    ones[0] = ones[1] = ones[2] = ones[3] = 1.0f;
    f32x4 pat[8];
    #pragma unroll
    for (int q = 0; q < 8; ++q) {
        const int4 nz = *(const int4*)&noisy[q * 1024 + t * 4];
        pat[q][0] = nz.x ? 1.0f : 0.0f;
        pat[q][1] = nz.y ? 1.0f : 0.0f;
        pat[q][2] = nz.z ? 1.0f : 0.0f;
        pat[q][3] = nz.w ? 1.0f : 0.0f;
    }
    const int row0 = blockIdx.x * 4;
    for (int r = 0; r < 4; ++r) {
        const int row = row0 + r;
        const int rn = noisy[row];          // uniform per block-row
        float* dst = mask_out + (size_t)row * B_DIM;
        if (rn) {
            #pragma unroll
            for (int q = 0; q < 8; ++q)
                *(f32x4*)(dst + q * 1024 + t * 4) = ones;
        } else {
            #pragma unroll
            for (int q = 0; q < 8; ++q)
                *(f32x4*)(dst + q * 1024 + t * 4) = pat[q];
        }
    }
}

// R9 + LDS chunk-swizzle (kills the measured 8.4M bank conflicts):
// staging layout is [row][32] bf16 (64B rows = 16-bank stride -> naive
// fragment reads are ~8-way conflicted). Fix per rule #21: LDS dest stays
// linear; the SOURCE 16B-chunk is XOR-permuted within each row's 64B
// (chunk ^= (row>>1)&3), and the fragment read applies the same involution.
__global__ __launch_bounds__(256, 3) void gemm_fused(
    const unsigned short* __restrict__ Vn, const unsigned short* __restrict__ Tn,
    const int* __restrict__ noisy,
    float* __restrict__ sim_out, float* __restrict__ part)
{
    // 48KB: 3 x (8KB A + 8KB B) staging; epilogue reuses first 32KB.
    __shared__ __align__(16) unsigned char smem[49152];

    const int tid  = threadIdx.x;
    const int wave = tid >> 6;
    const int lane = tid & 63;
    const int wr = wave >> 1;       // wave row (0..1)
    const int wc = wave & 1;        // wave col (0..1)

    // XCD-band mapping: xcd = bid&7 owns row band [xcd*8, xcd*8+8) panels;
    // column-panel-major within the band (proven FETCH win, R5: 77MB).
    const int bid = blockIdx.x;
    const int xcd = bid & 7;
    const int i   = bid >> 3;          // 0..511
    const int cp  = i >> 3;            // col panel 0..63 (slow)
    const int rp  = i & 7;             // row panel within band (fast)
    const int brow = (xcd * 8 + rp) * BM;
    const int bcol = cp * BN;

    // staging: lane -> LDS (row = lane>>2, chunk = lane&3); source chunk is
    // pre-swizzled so LDS(r,c) holds global chunk c ^ ((r>>1)&3).
    const int sr = lane >> 2;
    const int sc = (((lane & 3) ^ ((lane >> 3) & 3)) * 8);   // swizzled source chunk
    const int c0 = wave * 2;

    const int fr = lane & 15;
    // fragment read chunk: q ^ ((R>>1)&3) collapses to (lane>>4) ^ ((fr>>1)&3)
    const int ch = ((lane >> 4) ^ ((fr >> 1) & 3)) * 8;      // element offset

    // buf base (bytes): A at buf*16384, B at buf*16384 + 8192
#define STAGE(buf, k0) do {                                                        \
        _Pragma("unroll")                                                          \
        for (int q = 0; q < 2; ++q) {                                              \
            const int cw  = c0 + q;                                                \
            const int row = cw * 16 + sr;                                          \
            const unsigned short* ga = Vn + (size_t)(brow + row) * D_DIM + (k0) + sc; \
            const unsigned short* gb = Tn + (size_t)(bcol + row) * D_DIM + (k0) + sc; \
            __builtin_amdgcn_global_load_lds((gas_ptr)ga, (las_ptr)(smem + (buf) * 16384 + cw * 1024), 16, 0, 0); \
            __builtin_amdgcn_global_load_lds((gas_ptr)gb, (las_ptr)(smem + (buf) * 16384 + 8192 + cw * 1024), 16, 0, 0); \
        }                                                                          \
    } while (0)

    f32x4 acc[4][4] = {};              // sim^T fragments

    STAGE(0, 0);                       // 4 loads/wave in flight
    STAGE(1, BK);                      // 8 loads/wave in flight

    #pragma unroll
    for (int t = 0; t < KSTEPS; ++t) {
        const int cur = t % 3;
        // wait for tile t's 4 loads (tile t+1's 4 remain in flight);
        // only the last step drains fully.
        if (t < KSTEPS - 1) { asm volatile("s_waitcnt vmcnt(4)" ::: "memory"); }
        else                { asm volatile("s_waitcnt vmcnt(0)" ::: "memory"); }
        __builtin_amdgcn_sched_barrier(0);
        __builtin_amdgcn_s_barrier();      // all waves: tile t fully in LDS
        __builtin_amdgcn_sched_barrier(0);

        if (t + 2 < KSTEPS)
            STAGE((t + 2) % 3, (t + 2) * BK);   // refill; stays in flight
                                                // across the next barrier

        const unsigned short* Ab = (const unsigned short*)(smem + cur * 16384);
        const unsigned short* Bb = (const unsigned short*)(smem + cur * 16384 + 8192);
        bf16x8 af[4], bfr[4];
        #pragma unroll
        for (int m = 0; m < 4; ++m)
            af[m] = *(const bf16x8*)&Ab[(wr * 64 + m * 16 + fr) * BK + ch];
        #pragma unroll
        for (int n = 0; n < 4; ++n)
            bfr[n] = *(const bf16x8*)&Bb[(wc * 64 + n * 16 + fr) * BK + ch];

        // swapped operands: lane holds sim[m*16+(lane&15)][n*16+(lane>>4)*4+r]
        #pragma unroll
        for (int m = 0; m < 4; ++m)
            #pragma unroll
            for (int n = 0; n < 4; ++n)
                acc[m][n] = __builtin_amdgcn_mfma_f32_16x16x32_bf16(
                    bfr[n], af[m], acc[m][n], 0, 0, 0);
    }
#undef STAGE

    __syncthreads();   // all waves done reading staging bufs; smem reusable

    const float Tinv = 1.0f / 0.07f;
    const int ci = lane & 15;           // sim row within 16-block
    const int cg = lane >> 4;           // sim col group (4 cols each)

    // ---- rowsum partials (registers -> LDS combine -> one store/row) ----
    int rn[4];
    #pragma unroll
    for (int m = 0; m < 4; ++m)
        rn[m] = noisy[brow + wr * 64 + m * 16 + ci];
    int4 cn4[4];
    #pragma unroll
    for (int n = 0; n < 4; ++n)
        cn4[n] = *(const int4*)&noisy[bcol + wc * 64 + n * 16 + cg * 4];

    float* lsum = (float*)smem;        // [2][128]
    #pragma unroll
    for (int m = 0; m < 4; ++m) {
        float partial = 0.0f;
        #pragma unroll
        for (int n = 0; n < 4; ++n) {
            const f32x4 s = acc[m][n];
            partial += (rn[m] | cn4[n].x) ? __expf(s[0] * Tinv) : 0.0f;
            partial += (rn[m] | cn4[n].y) ? __expf(s[1] * Tinv) : 0.0f;
            partial += (rn[m] | cn4[n].z) ? __expf(s[2] * Tinv) : 0.0f;
            partial += (rn[m] | cn4[n].w) ? __expf(s[3] * Tinv) : 0.0f;
        }
        partial += __shfl_xor(partial, 16);
        partial += __shfl_xor(partial, 32);
        if (lane < 16) lsum[wc * 128 + wr * 64 + m * 16 + ci] = partial;
    }
    __syncthreads();
    if (tid < 128)
        part[(size_t)cp * B_DIM + brow + tid] = lsum[tid] + lsum[128 + tid];

    // ---- sim stores: restage through LDS for row-contiguous segments ----
    // fbuf = f32[64][128], swizzle byte ^= (row&7)<<6 (2-way max both sides).
    const int l31  = tid & 31;
    const int rsub = tid >> 5;          // 0..7
    for (int h = 0; h < 2; ++h) {
        __syncthreads();                // lsum reads done / prev phase done
        if (wr == h) {
            #pragma unroll
            for (int m = 0; m < 4; ++m) {
                const int row = m * 16 + ci;            // 0..63
                #pragma unroll
                for (int n = 0; n < 4; ++n) {
                    const int col = wc * 64 + n * 16 + cg * 4;
                    int byte = (row * 128 + col) * 4;
                    byte ^= (row & 7) << 6;
                    *(f32x4*)(smem + byte) = acc[m][n];
                }
            }
        }
        __syncthreads();
        #pragma unroll
        for (int j = 0; j < 8; ++j) {
            const int row = j * 8 + rsub;               // 0..63
            int byte = (row * 128 + l31 * 4) * 4;
            byte ^= (row & 7) << 6;
            const f32x4 v = *(const f32x4*)(smem + byte);
            const int grow = brow + h * 64 + row;
            *(f32x4*)(sim_out + (size_t)grow * B_DIM + bcol + l31 * 4) = v;
        }
    }
}

// stage 1: 32 blocks x 256 rows -> per-block sum of log(rowsum+eps)
__global__ __launch_bounds__(256) void loss_stage1(
    const float* __restrict__ part, float* __restrict__ s1)
{
    __shared__ float wsum[4];
    const int row = blockIdx.x * 256 + threadIdx.x;
    float s = 0.0f;
    #pragma unroll
    for (int c = 0; c < NCP; ++c)
        s += part[(size_t)c * B_DIM + row];
    float l = logf(s + 1e-8f);
    #pragma unroll
    for (int off = 32; off; off >>= 1) l += __shfl_xor(l, off);
    if ((threadIdx.x & 63) == 0) wsum[threadIdx.x >> 6] = l;
    __syncthreads();
    if (threadIdx.x == 0)
        s1[blockIdx.x] = (wsum[0] + wsum[1]) + (wsum[2] + wsum[3]);
}

// stage 2: single wave sums the 32 block partials
__global__ __launch_bounds__(64) void loss_stage2(
    const float* __restrict__ s1, float* __restrict__ out)
{
    const int lane = threadIdx.x;
    float s = (lane < 32) ? s1[lane] : 0.0f;
    #pragma unroll
    for (int off = 32; off; off >>= 1) s += __shfl_xor(s, off);
    if (lane == 0) {
        const float loss = s * (1.0f / (float)B_DIM);
        out[0] = loss;   // complementary_loss
        out[1] = loss;   // brownian_loss (identical chain)
    }
}

extern "C" void kernel_launch(void* const* d_in, const int* in_sizes, int n_in,
                              void* d_out, int out_size, void* d_ws, size_t ws_size,
                              hipStream_t stream) {
    const float* V = (const float*)d_in[0];
    const float* T = (const float*)d_in[1];
    const int* noisy = (const int*)d_in[3];   // confident_clean_mask (d_in[2]) unused
    float* out = (float*)d_out;

    float* mask_out = out + 2;
    float* sim_out  = out + 2 + (size_t)B_DIM * B_DIM;

    unsigned short* Vn = (unsigned short*)d_ws;                       // 8 MB
    unsigned short* Tn = Vn + (size_t)B_DIM * D_DIM;                  // 8 MB
    float* part = (float*)(Tn + (size_t)B_DIM * D_DIM);               // 2 MB
    float* s1   = part + (size_t)NCP * B_DIM;                         // 128 B

    normalize_rows<<<(2 * B_DIM) / 4, 256, 0, stream>>>(V, T, Vn, Tn);
    mask_fill<<<B_DIM / 4, 256, 0, stream>>>(noisy, mask_out);
    gemm_fused<<<64 * 64, 256, 0, stream>>>(Vn, Tn, noisy, sim_out, part);
    loss_stage1<<<32, 256, 0, stream>>>(part, s1);
    loss_stage2<<<1, 64, 0, stream>>>(s1, out);
}

// Round 11
// 236.605 us; speedup vs baseline: 1.1007x; 1.0469x over previous
//
#include <hip/hip_runtime.h>
#include <hip/hip_bf16.h>
#include <cstdint>

#define B_DIM 8192
#define D_DIM 512
#define BM 128
#define BN 128
#define BK 32
#define KSTEPS (D_DIM / BK)   // 16
#define NCP 64                // col panels (slots in part[])

typedef __attribute__((ext_vector_type(8))) short bf16x8;
typedef __attribute__((ext_vector_type(4))) float f32x4;

typedef __attribute__((address_space(1))) const void* gas_ptr;
typedef __attribute__((address_space(3))) void* las_ptr;

static __device__ __forceinline__ unsigned short f2bf(float x) {
    __hip_bfloat16 h = __float2bfloat16(x);
    return *reinterpret_cast<unsigned short*>(&h);
}

// One wave per row: L2-normalize (f32) and emit bf16.
__global__ __launch_bounds__(256) void normalize_rows(
    const float* __restrict__ V, const float* __restrict__ T,
    unsigned short* __restrict__ Vn, unsigned short* __restrict__ Tn)
{
    const int wave = threadIdx.x >> 6;
    const int lane = threadIdx.x & 63;
    const int row = blockIdx.x * 4 + wave;     // 0..16383 (V rows then T rows)
    const float* src;
    unsigned short* dst;
    if (row < B_DIM) {
        src = V + (size_t)row * D_DIM;
        dst = Vn + (size_t)row * D_DIM;
    } else {
        src = T + (size_t)(row - B_DIM) * D_DIM;
        dst = Tn + (size_t)(row - B_DIM) * D_DIM;
    }
    float4 a = *(const float4*)(src + lane * 4);
    float4 b = *(const float4*)(src + 256 + lane * 4);
    float ss = a.x*a.x + a.y*a.y + a.z*a.z + a.w*a.w
             + b.x*b.x + b.y*b.y + b.z*b.z + b.w*b.w;
    #pragma unroll
    for (int off = 32; off; off >>= 1) ss += __shfl_xor(ss, off);
    const float inv = 1.0f / fmaxf(sqrtf(ss), 1e-12f);
    ushort4 oa, ob;
    oa.x = f2bf(a.x * inv); oa.y = f2bf(a.y * inv);
    oa.z = f2bf(a.z * inv); oa.w = f2bf(a.w * inv);
    ob.x = f2bf(b.x * inv); ob.y = f2bf(b.y * inv);
    ob.z = f2bf(b.z * inv); ob.w = f2bf(b.w * inv);
    *(ushort4*)(dst + lane * 4) = oa;
    *(ushort4*)(dst + 256 + lane * 4) = ob;
}

// Fused GEMM + mask kernel. Grid 6144, period-24 interleave:
//   bid%24 in [0,16)  -> gemm block, gemm_id = (bid/24)*16 + bid%24
//   bid%24 in [16,24) -> mask block, mask_id = (bid/24)*8 + bid%24-16
// 24%8==0 keeps gemm_id&7 == bid&7, preserving the XCD-band property.
// Mask blocks are pure store streams that fill gemm's vmcnt/barrier stall
// bubbles on the same CUs (disjoint pipes: store vs MFMA/LDS).
__global__ __launch_bounds__(256, 3) void gemm_mask(
    const unsigned short* __restrict__ Vn, const unsigned short* __restrict__ Tn,
    const int* __restrict__ noisy,
    float* __restrict__ sim_out, float* __restrict__ mask_out,
    float* __restrict__ part)
{
    // 48KB: 3 x (8KB A + 8KB B) staging; epilogue reuses first 32KB.
    __shared__ __align__(16) unsigned char smem[49152];

    const int bid = blockIdx.x;
    const int grp = bid / 24;
    const int jj  = bid % 24;

    if (jj >= 16) {
        // ---------------- mask path ----------------
        const int mask_id = grp * 8 + (jj - 16);     // 0..2047
        const int t = threadIdx.x;
        f32x4 ones;
        ones[0] = ones[1] = ones[2] = ones[3] = 1.0f;
        f32x4 pat[8];
        #pragma unroll
        for (int q = 0; q < 8; ++q) {
            const int4 nz = *(const int4*)&noisy[q * 1024 + t * 4];
            pat[q][0] = nz.x ? 1.0f : 0.0f;
            pat[q][1] = nz.y ? 1.0f : 0.0f;
            pat[q][2] = nz.z ? 1.0f : 0.0f;
            pat[q][3] = nz.w ? 1.0f : 0.0f;
        }
        const int row0 = mask_id * 4;
        for (int r = 0; r < 4; ++r) {
            const int row = row0 + r;
            const int rn = noisy[row];          // uniform per block-row
            float* dst = mask_out + (size_t)row * B_DIM;
            if (rn) {
                #pragma unroll
                for (int q = 0; q < 8; ++q)
                    *(f32x4*)(dst + q * 1024 + t * 4) = ones;
            } else {
                #pragma unroll
                for (int q = 0; q < 8; ++q)
                    *(f32x4*)(dst + q * 1024 + t * 4) = pat[q];
            }
        }
        return;
    }

    // ---------------- gemm path (R10 body) ----------------
    const int gemm_id = grp * 16 + jj;               // 0..4095

    const int tid  = threadIdx.x;
    const int wave = tid >> 6;
    const int lane = tid & 63;
    const int wr = wave >> 1;       // wave row (0..1)
    const int wc = wave & 1;        // wave col (0..1)

    // XCD-band mapping: xcd = gemm_id&7 (== bid&7) owns row band; col-panel-major.
    const int xcd = gemm_id & 7;
    const int i   = gemm_id >> 3;      // 0..511
    const int cp  = i >> 3;            // col panel 0..63 (slow)
    const int rp  = i & 7;             // row panel within band (fast)
    const int brow = (xcd * 8 + rp) * BM;
    const int bcol = cp * BN;

    // staging: lane -> LDS (row = lane>>2, chunk = lane&3); source chunk is
    // pre-swizzled so LDS(r,c) holds global chunk c ^ ((r>>1)&3).
    const int sr = lane >> 2;
    const int sc = (((lane & 3) ^ ((lane >> 3) & 3)) * 8);   // swizzled source chunk
    const int c0 = wave * 2;

    const int fr = lane & 15;
    // fragment read chunk: q ^ ((R>>1)&3) collapses to (lane>>4) ^ ((fr>>1)&3)
    const int ch = ((lane >> 4) ^ ((fr >> 1) & 3)) * 8;      // element offset

    // buf base (bytes): A at buf*16384, B at buf*16384 + 8192
#define STAGE(buf, k0) do {                                                        \
        _Pragma("unroll")                                                          \
        for (int q = 0; q < 2; ++q) {                                              \
            const int cw  = c0 + q;                                                \
            const int row = cw * 16 + sr;                                          \
            const unsigned short* ga = Vn + (size_t)(brow + row) * D_DIM + (k0) + sc; \
            const unsigned short* gb = Tn + (size_t)(bcol + row) * D_DIM + (k0) + sc; \
            __builtin_amdgcn_global_load_lds((gas_ptr)ga, (las_ptr)(smem + (buf) * 16384 + cw * 1024), 16, 0, 0); \
            __builtin_amdgcn_global_load_lds((gas_ptr)gb, (las_ptr)(smem + (buf) * 16384 + 8192 + cw * 1024), 16, 0, 0); \
        }                                                                          \
    } while (0)

    f32x4 acc[4][4] = {};              // sim^T fragments

    STAGE(0, 0);                       // 4 loads/wave in flight
    STAGE(1, BK);                      // 8 loads/wave in flight

    #pragma unroll
    for (int t = 0; t < KSTEPS; ++t) {
        const int cur = t % 3;
        // wait for tile t's 4 loads (tile t+1's 4 remain in flight);
        // only the last step drains fully.
        if (t < KSTEPS - 1) { asm volatile("s_waitcnt vmcnt(4)" ::: "memory"); }
        else                { asm volatile("s_waitcnt vmcnt(0)" ::: "memory"); }
        __builtin_amdgcn_sched_barrier(0);
        __builtin_amdgcn_s_barrier();      // all waves: tile t fully in LDS
        __builtin_amdgcn_sched_barrier(0);

        if (t + 2 < KSTEPS)
            STAGE((t + 2) % 3, (t + 2) * BK);   // refill; stays in flight
                                                // across the next barrier

        const unsigned short* Ab = (const unsigned short*)(smem + cur * 16384);
        const unsigned short* Bb = (const unsigned short*)(smem + cur * 16384 + 8192);
        bf16x8 af[4], bfr[4];
        #pragma unroll
        for (int m = 0; m < 4; ++m)
            af[m] = *(const bf16x8*)&Ab[(wr * 64 + m * 16 + fr) * BK + ch];
        #pragma unroll
        for (int n = 0; n < 4; ++n)
            bfr[n] = *(const bf16x8*)&Bb[(wc * 64 + n * 16 + fr) * BK + ch];

        // swapped operands: lane holds sim[m*16+(lane&15)][n*16+(lane>>4)*4+r]
        #pragma unroll
        for (int m = 0; m < 4; ++m)
            #pragma unroll
            for (int n = 0; n < 4; ++n)
                acc[m][n] = __builtin_amdgcn_mfma_f32_16x16x32_bf16(
                    bfr[n], af[m], acc[m][n], 0, 0, 0);
    }
#undef STAGE

    __syncthreads();   // all waves done reading staging bufs; smem reusable

    const float Tinv = 1.0f / 0.07f;
    const int ci = lane & 15;           // sim row within 16-block
    const int cg = lane >> 4;           // sim col group (4 cols each)

    // ---- rowsum partials (registers -> LDS combine -> one store/row) ----
    int rn[4];
    #pragma unroll
    for (int m = 0; m < 4; ++m)
        rn[m] = noisy[brow + wr * 64 + m * 16 + ci];
    int4 cn4[4];
    #pragma unroll
    for (int n = 0; n < 4; ++n)
        cn4[n] = *(const int4*)&noisy[bcol + wc * 64 + n * 16 + cg * 4];

    float* lsum = (float*)smem;        // [2][128]
    #pragma unroll
    for (int m = 0; m < 4; ++m) {
        float partial = 0.0f;
        #pragma unroll
        for (int n = 0; n < 4; ++n) {
            const f32x4 s = acc[m][n];
            partial += (rn[m] | cn4[n].x) ? __expf(s[0] * Tinv) : 0.0f;
            partial += (rn[m] | cn4[n].y) ? __expf(s[1] * Tinv) : 0.0f;
            partial += (rn[m] | cn4[n].z) ? __expf(s[2] * Tinv) : 0.0f;
            partial += (rn[m] | cn4[n].w) ? __expf(s[3] * Tinv) : 0.0f;
        }
        partial += __shfl_xor(partial, 16);
        partial += __shfl_xor(partial, 32);
        if (lane < 16) lsum[wc * 128 + wr * 64 + m * 16 + ci] = partial;
    }
    __syncthreads();
    if (tid < 128)
        part[(size_t)cp * B_DIM + brow + tid] = lsum[tid] + lsum[128 + tid];

    // ---- sim stores: restage through LDS for row-contiguous segments ----
    // fbuf = f32[64][128], swizzle byte ^= (row&7)<<6 (2-way max both sides).
    const int l31  = tid & 31;
    const int rsub = tid >> 5;          // 0..7
    for (int h = 0; h < 2; ++h) {
        __syncthreads();                // lsum reads done / prev phase done
        if (wr == h) {
            #pragma unroll
            for (int m = 0; m < 4; ++m) {
                const int row = m * 16 + ci;            // 0..63
                #pragma unroll
                for (int n = 0; n < 4; ++n) {
                    const int col = wc * 64 + n * 16 + cg * 4;
                    int byte = (row * 128 + col) * 4;
                    byte ^= (row & 7) << 6;
                    *(f32x4*)(smem + byte) = acc[m][n];
                }
            }
        }
        __syncthreads();
        #pragma unroll
        for (int j = 0; j < 8; ++j) {
            const int row = j * 8 + rsub;               // 0..63
            int byte = (row * 128 + l31 * 4) * 4;
            byte ^= (row & 7) << 6;
            const f32x4 v = *(const f32x4*)(smem + byte);
            const int grow = brow + h * 64 + row;
            *(f32x4*)(sim_out + (size_t)grow * B_DIM + bcol + l31 * 4) = v;
        }
    }
}

// stage 1: 32 blocks x 256 rows -> per-block sum of log(rowsum+eps)
__global__ __launch_bounds__(256) void loss_stage1(
    const float* __restrict__ part, float* __restrict__ s1)
{
    __shared__ float wsum[4];
    const int row = blockIdx.x * 256 + threadIdx.x;
    float s = 0.0f;
    #pragma unroll
    for (int c = 0; c < NCP; ++c)
        s += part[(size_t)c * B_DIM + row];
    float l = logf(s + 1e-8f);
    #pragma unroll
    for (int off = 32; off; off >>= 1) l += __shfl_xor(l, off);
    if ((threadIdx.x & 63) == 0) wsum[threadIdx.x >> 6] = l;
    __syncthreads();
    if (threadIdx.x == 0)
        s1[blockIdx.x] = (wsum[0] + wsum[1]) + (wsum[2] + wsum[3]);
}

// stage 2: single wave sums the 32 block partials
__global__ __launch_bounds__(64) void loss_stage2(
    const float* __restrict__ s1, float* __restrict__ out)
{
    const int lane = threadIdx.x;
    float s = (lane < 32) ? s1[lane] : 0.0f;
    #pragma unroll
    for (int off = 32; off; off >>= 1) s += __shfl_xor(s, off);
    if (lane == 0) {
        const float loss = s * (1.0f / (float)B_DIM);
        out[0] = loss;   // complementary_loss
        out[1] = loss;   // brownian_loss (identical chain)
    }
}

extern "C" void kernel_launch(void* const* d_in, const int* in_sizes, int n_in,
                              void* d_out, int out_size, void* d_ws, size_t ws_size,
                              hipStream_t stream) {
    const float* V = (const float*)d_in[0];
    const float* T = (const float*)d_in[1];
    const int* noisy = (const int*)d_in[3];   // confident_clean_mask (d_in[2]) unused
    float* out = (float*)d_out;

    float* mask_out = out + 2;
    float* sim_out  = out + 2 + (size_t)B_DIM * B_DIM;

    unsigned short* Vn = (unsigned short*)d_ws;                       // 8 MB
    unsigned short* Tn = Vn + (size_t)B_DIM * D_DIM;                  // 8 MB
    float* part = (float*)(Tn + (size_t)B_DIM * D_DIM);               // 2 MB
    float* s1   = part + (size_t)NCP * B_DIM;                         // 128 B

    normalize_rows<<<(2 * B_DIM) / 4, 256, 0, stream>>>(V, T, Vn, Tn);
    gemm_mask<<<6144, 256, 0, stream>>>(Vn, Tn, noisy, sim_out, mask_out, part);
    loss_stage1<<<32, 256, 0, stream>>>(part, s1);
    loss_stage2<<<1, 64, 0, stream>>>(s1, out);
}

// Round 12
// 204.068 us; speedup vs baseline: 1.2762x; 1.1594x over previous
//
#include <hip/hip_runtime.h>
#include <hip/hip_bf16.h>
#include <cstdint>

#define B_DIM 8192
#define D_DIM 512
#define BM 128
#define BN 128
#define BK 32
#define KSTEPS (D_DIM / BK)   // 16
#define NCP 64                // col panels (slots in part[])

typedef __attribute__((ext_vector_type(8))) short bf16x8;
typedef __attribute__((ext_vector_type(4))) float f32x4;

typedef __attribute__((address_space(1))) const void* gas_ptr;
typedef __attribute__((address_space(3))) void* las_ptr;

static __device__ __forceinline__ unsigned short f2bf(float x) {
    __hip_bfloat16 h = __float2bfloat16(x);
    return *reinterpret_cast<unsigned short*>(&h);
}

// One wave per row: L2-normalize (f32) and emit bf16.
__global__ __launch_bounds__(256) void normalize_rows(
    const float* __restrict__ V, const float* __restrict__ T,
    unsigned short* __restrict__ Vn, unsigned short* __restrict__ Tn)
{
    const int wave = threadIdx.x >> 6;
    const int lane = threadIdx.x & 63;
    const int row = blockIdx.x * 4 + wave;     // 0..16383 (V rows then T rows)
    const float* src;
    unsigned short* dst;
    if (row < B_DIM) {
        src = V + (size_t)row * D_DIM;
        dst = Vn + (size_t)row * D_DIM;
    } else {
        src = T + (size_t)(row - B_DIM) * D_DIM;
        dst = Tn + (size_t)(row - B_DIM) * D_DIM;
    }
    float4 a = *(const float4*)(src + lane * 4);
    float4 b = *(const float4*)(src + 256 + lane * 4);
    float ss = a.x*a.x + a.y*a.y + a.z*a.z + a.w*a.w
             + b.x*b.x + b.y*b.y + b.z*b.z + b.w*b.w;
    #pragma unroll
    for (int off = 32; off; off >>= 1) ss += __shfl_xor(ss, off);
    const float inv = 1.0f / fmaxf(sqrtf(ss), 1e-12f);
    ushort4 oa, ob;
    oa.x = f2bf(a.x * inv); oa.y = f2bf(a.y * inv);
    oa.z = f2bf(a.z * inv); oa.w = f2bf(a.w * inv);
    ob.x = f2bf(b.x * inv); ob.y = f2bf(b.y * inv);
    ob.z = f2bf(b.z * inv); ob.w = f2bf(b.w * inv);
    *(ushort4*)(dst + lane * 4) = oa;
    *(ushort4*)(dst + 256 + lane * 4) = ob;
}

// Fused GEMM + mask kernel. Grid 6144, period-24 interleave:
//   bid%24 in [0,16)  -> gemm block, gemm_id = (bid/24)*16 + bid%24
//   bid%24 in [16,24) -> mask block, mask_id = (bid/24)*8 + bid%24-16
// Mask blocks fill gemm's stall bubbles (proven ~11us, R11).
// R12: nt stores on sim/mask (512B+ contiguous runs = full 128B sectors,
// no RMW; keeps 537MB of dead-on-write data out of L2) and 2-buffer
// staging (32KB LDS) -> 4 blocks/CU, 16 waves/CU.
__global__ __launch_bounds__(256, 4) void gemm_mask(
    const unsigned short* __restrict__ Vn, const unsigned short* __restrict__ Tn,
    const int* __restrict__ noisy,
    float* __restrict__ sim_out, float* __restrict__ mask_out,
    float* __restrict__ part)
{
    // 32KB: 2 x (8KB A + 8KB B) staging; epilogue reuses all 32KB.
    __shared__ __align__(16) unsigned char smem[32768];

    const int bid = blockIdx.x;
    const int grp = bid / 24;
    const int jj  = bid % 24;

    if (jj >= 16) {
        // ---------------- mask path ----------------
        const int mask_id = grp * 8 + (jj - 16);     // 0..2047
        const int t = threadIdx.x;
        f32x4 ones;
        ones[0] = ones[1] = ones[2] = ones[3] = 1.0f;
        f32x4 pat[8];
        #pragma unroll
        for (int q = 0; q < 8; ++q) {
            const int4 nz = *(const int4*)&noisy[q * 1024 + t * 4];
            pat[q][0] = nz.x ? 1.0f : 0.0f;
            pat[q][1] = nz.y ? 1.0f : 0.0f;
            pat[q][2] = nz.z ? 1.0f : 0.0f;
            pat[q][3] = nz.w ? 1.0f : 0.0f;
        }
        const int row0 = mask_id * 4;
        for (int r = 0; r < 4; ++r) {
            const int row = row0 + r;
            const int rn = noisy[row];          // uniform per block-row
            float* dst = mask_out + (size_t)row * B_DIM;
            if (rn) {
                #pragma unroll
                for (int q = 0; q < 8; ++q)
                    __builtin_nontemporal_store(ones, (f32x4*)(dst + q * 1024 + t * 4));
            } else {
                #pragma unroll
                for (int q = 0; q < 8; ++q)
                    __builtin_nontemporal_store(pat[q], (f32x4*)(dst + q * 1024 + t * 4));
            }
        }
        return;
    }

    // ---------------- gemm path ----------------
    const int gemm_id = grp * 16 + jj;               // 0..4095

    const int tid  = threadIdx.x;
    const int wave = tid >> 6;
    const int lane = tid & 63;
    const int wr = wave >> 1;       // wave row (0..1)
    const int wc = wave & 1;        // wave col (0..1)

    // XCD-band mapping: xcd = gemm_id&7 (== bid&7) owns row band; col-panel-major.
    const int xcd = gemm_id & 7;
    const int i   = gemm_id >> 3;      // 0..511
    const int cp  = i >> 3;            // col panel 0..63 (slow)
    const int rp  = i & 7;             // row panel within band (fast)
    const int brow = (xcd * 8 + rp) * BM;
    const int bcol = cp * BN;

    // staging: lane -> LDS (row = lane>>2, chunk = lane&3); source chunk is
    // pre-swizzled so LDS(r,c) holds global chunk c ^ ((r>>1)&3).
    const int sr = lane >> 2;
    const int sc = (((lane & 3) ^ ((lane >> 3) & 3)) * 8);   // swizzled source chunk
    const int c0 = wave * 2;

    const int fr = lane & 15;
    // fragment read chunk: q ^ ((R>>1)&3) collapses to (lane>>4) ^ ((fr>>1)&3)
    const int ch = ((lane >> 4) ^ ((fr >> 1) & 3)) * 8;      // element offset

    // buf base (bytes): A at buf*16384, B at buf*16384 + 8192
#define STAGE(buf, k0) do {                                                        \
        _Pragma("unroll")                                                          \
        for (int q = 0; q < 2; ++q) {                                              \
            const int cw  = c0 + q;                                                \
            const int row = cw * 16 + sr;                                          \
            const unsigned short* ga = Vn + (size_t)(brow + row) * D_DIM + (k0) + sc; \
            const unsigned short* gb = Tn + (size_t)(bcol + row) * D_DIM + (k0) + sc; \
            __builtin_amdgcn_global_load_lds((gas_ptr)ga, (las_ptr)(smem + (buf) * 16384 + cw * 1024), 16, 0, 0); \
            __builtin_amdgcn_global_load_lds((gas_ptr)gb, (las_ptr)(smem + (buf) * 16384 + 8192 + cw * 1024), 16, 0, 0); \
        }                                                                          \
    } while (0)

    f32x4 acc[4][4] = {};              // sim^T fragments

    STAGE(0, 0);                       // tile 0 in flight

    #pragma unroll
    for (int t = 0; t < KSTEPS; ++t) {
        const int cur = t & 1;
        // Only tile t's 4 loads are outstanding here (issued one full
        // MFMA-phase ago). Drain them, barrier, THEN issue tile t+1 so it
        // stays in flight across this iteration's MFMA phase (and the next
        // barrier) — prefetch is never drained by the wait.
        asm volatile("s_waitcnt vmcnt(0)" ::: "memory");
        __builtin_amdgcn_sched_barrier(0);
        __builtin_amdgcn_s_barrier();      // all waves: tile t fully in LDS
        __builtin_amdgcn_sched_barrier(0);

        if (t + 1 < KSTEPS)
            STAGE((t + 1) & 1, (t + 1) * BK);   // buf[(t+1)&1] last read in
                                                // iter t-1, before barrier(t)

        const unsigned short* Ab = (const unsigned short*)(smem + cur * 16384);
        const unsigned short* Bb = (const unsigned short*)(smem + cur * 16384 + 8192);
        bf16x8 af[4], bfr[4];
        #pragma unroll
        for (int m = 0; m < 4; ++m)
            af[m] = *(const bf16x8*)&Ab[(wr * 64 + m * 16 + fr) * BK + ch];
        #pragma unroll
        for (int n = 0; n < 4; ++n)
            bfr[n] = *(const bf16x8*)&Bb[(wc * 64 + n * 16 + fr) * BK + ch];

        // swapped operands: lane holds sim[m*16+(lane&15)][n*16+(lane>>4)*4+r]
        #pragma unroll
        for (int m = 0; m < 4; ++m)
            #pragma unroll
            for (int n = 0; n < 4; ++n)
                acc[m][n] = __builtin_amdgcn_mfma_f32_16x16x32_bf16(
                    bfr[n], af[m], acc[m][n], 0, 0, 0);
    }
#undef STAGE

    __syncthreads();   // all waves done reading staging bufs; smem reusable

    const float Tinv = 1.0f / 0.07f;
    const int ci = lane & 15;           // sim row within 16-block
    const int cg = lane >> 4;           // sim col group (4 cols each)

    // ---- rowsum partials (registers -> LDS combine -> one store/row) ----
    int rn[4];
    #pragma unroll
    for (int m = 0; m < 4; ++m)
        rn[m] = noisy[brow + wr * 64 + m * 16 + ci];
    int4 cn4[4];
    #pragma unroll
    for (int n = 0; n < 4; ++n)
        cn4[n] = *(const int4*)&noisy[bcol + wc * 64 + n * 16 + cg * 4];

    float* lsum = (float*)smem;        // [2][128]
    #pragma unroll
    for (int m = 0; m < 4; ++m) {
        float partial = 0.0f;
        #pragma unroll
        for (int n = 0; n < 4; ++n) {
            const f32x4 s = acc[m][n];
            partial += (rn[m] | cn4[n].x) ? __expf(s[0] * Tinv) : 0.0f;
            partial += (rn[m] | cn4[n].y) ? __expf(s[1] * Tinv) : 0.0f;
            partial += (rn[m] | cn4[n].z) ? __expf(s[2] * Tinv) : 0.0f;
            partial += (rn[m] | cn4[n].w) ? __expf(s[3] * Tinv) : 0.0f;
        }
        partial += __shfl_xor(partial, 16);
        partial += __shfl_xor(partial, 32);
        if (lane < 16) lsum[wc * 128 + wr * 64 + m * 16 + ci] = partial;
    }
    __syncthreads();
    if (tid < 128)
        part[(size_t)cp * B_DIM + brow + tid] = lsum[tid] + lsum[128 + tid];

    // ---- sim stores: restage through LDS, nt stores (512B runs = full
    // 128B sectors, no RMW; sim is dead-on-write, keep it out of L2) ----
    const int l31  = tid & 31;
    const int rsub = tid >> 5;          // 0..7
    for (int h = 0; h < 2; ++h) {
        __syncthreads();                // lsum reads done / prev phase done
        if (wr == h) {
            #pragma unroll
            for (int m = 0; m < 4; ++m) {
                const int row = m * 16 + ci;            // 0..63
                #pragma unroll
                for (int n = 0; n < 4; ++n) {
                    const int col = wc * 64 + n * 16 + cg * 4;
                    int byte = (row * 128 + col) * 4;
                    byte ^= (row & 7) << 6;
                    *(f32x4*)(smem + byte) = acc[m][n];
                }
            }
        }
        __syncthreads();
        #pragma unroll
        for (int j = 0; j < 8; ++j) {
            const int row = j * 8 + rsub;               // 0..63
            int byte = (row * 128 + l31 * 4) * 4;
            byte ^= (row & 7) << 6;
            const f32x4 v = *(const f32x4*)(smem + byte);
            const int grow = brow + h * 64 + row;
            __builtin_nontemporal_store(v,
                (f32x4*)(sim_out + (size_t)grow * B_DIM + bcol + l31 * 4));
        }
    }
}

// stage 1: 32 blocks x 256 rows -> per-block sum of log(rowsum+eps)
__global__ __launch_bounds__(256) void loss_stage1(
    const float* __restrict__ part, float* __restrict__ s1)
{
    __shared__ float wsum[4];
    const int row = blockIdx.x * 256 + threadIdx.x;
    float s = 0.0f;
    #pragma unroll
    for (int c = 0; c < NCP; ++c)
        s += part[(size_t)c * B_DIM + row];
    float l = logf(s + 1e-8f);
    #pragma unroll
    for (int off = 32; off; off >>= 1) l += __shfl_xor(l, off);
    if ((threadIdx.x & 63) == 0) wsum[threadIdx.x >> 6] = l;
    __syncthreads();
    if (threadIdx.x == 0)
        s1[blockIdx.x] = (wsum[0] + wsum[1]) + (wsum[2] + wsum[3]);
}

// stage 2: single wave sums the 32 block partials
__global__ __launch_bounds__(64) void loss_stage2(
    const float* __restrict__ s1, float* __restrict__ out)
{
    const int lane = threadIdx.x;
    float s = (lane < 32) ? s1[lane] : 0.0f;
    #pragma unroll
    for (int off = 32; off; off >>= 1) s += __shfl_xor(s, off);
    if (lane == 0) {
        const float loss = s * (1.0f / (float)B_DIM);
        out[0] = loss;   // complementary_loss
        out[1] = loss;   // brownian_loss (identical chain)
    }
}

extern "C" void kernel_launch(void* const* d_in, const int* in_sizes, int n_in,
                              void* d_out, int out_size, void* d_ws, size_t ws_size,
                              hipStream_t stream) {
    const float* V = (const float*)d_in[0];
    const float* T = (const float*)d_in[1];
    const int* noisy = (const int*)d_in[3];   // confident_clean_mask (d_in[2]) unused
    float* out = (float*)d_out;

    float* mask_out = out + 2;
    float* sim_out  = out + 2 + (size_t)B_DIM * B_DIM;

    unsigned short* Vn = (unsigned short*)d_ws;                       // 8 MB
    unsigned short* Tn = Vn + (size_t)B_DIM * D_DIM;                  // 8 MB
    float* part = (float*)(Tn + (size_t)B_DIM * D_DIM);               // 2 MB
    float* s1   = part + (size_t)NCP * B_DIM;                         // 128 B

    normalize_rows<<<(2 * B_DIM) / 4, 256, 0, stream>>>(V, T, Vn, Tn);
    gemm_mask<<<6144, 256, 0, stream>>>(Vn, Tn, noisy, sim_out, mask_out, part);
    loss_stage1<<<32, 256, 0, stream>>>(part, s1);
    loss_stage2<<<1, 64, 0, stream>>>(s1, out);
}

// Round 13
// 172.436 us; speedup vs baseline: 1.5103x; 1.1834x over previous
//
#include <hip/hip_runtime.h>
#include <hip/hip_bf16.h>
#include <cstdint>

#define B_DIM 8192
#define D_DIM 512
#define BM 128
#define BN 256
#define BK 32
#define KSTEPS (D_DIM / BK)   // 16
#define NCP 32                // col panels (slots in part[])

typedef __attribute__((ext_vector_type(8))) short bf16x8;
typedef __attribute__((ext_vector_type(4))) float f32x4;

typedef __attribute__((address_space(1))) const void* gas_ptr;
typedef __attribute__((address_space(3))) void* las_ptr;

static __device__ __forceinline__ unsigned short f2bf(float x) {
    __hip_bfloat16 h = __float2bfloat16(x);
    return *reinterpret_cast<unsigned short*>(&h);
}

// One wave per row: L2-normalize (f32) and emit bf16.
__global__ __launch_bounds__(256) void normalize_rows(
    const float* __restrict__ V, const float* __restrict__ T,
    unsigned short* __restrict__ Vn, unsigned short* __restrict__ Tn)
{
    const int wave = threadIdx.x >> 6;
    const int lane = threadIdx.x & 63;
    const int row = blockIdx.x * 4 + wave;     // 0..16383 (V rows then T rows)
    const float* src;
    unsigned short* dst;
    if (row < B_DIM) {
        src = V + (size_t)row * D_DIM;
        dst = Vn + (size_t)row * D_DIM;
    } else {
        src = T + (size_t)(row - B_DIM) * D_DIM;
        dst = Tn + (size_t)(row - B_DIM) * D_DIM;
    }
    float4 a = *(const float4*)(src + lane * 4);
    float4 b = *(const float4*)(src + 256 + lane * 4);
    float ss = a.x*a.x + a.y*a.y + a.z*a.z + a.w*a.w
             + b.x*b.x + b.y*b.y + b.z*b.z + b.w*b.w;
    #pragma unroll
    for (int off = 32; off; off >>= 1) ss += __shfl_xor(ss, off);
    const float inv = 1.0f / fmaxf(sqrtf(ss), 1e-12f);
    ushort4 oa, ob;
    oa.x = f2bf(a.x * inv); oa.y = f2bf(a.y * inv);
    oa.z = f2bf(a.z * inv); oa.w = f2bf(a.w * inv);
    ob.x = f2bf(b.x * inv); ob.y = f2bf(b.y * inv);
    ob.z = f2bf(b.z * inv); ob.w = f2bf(b.w * inv);
    *(ushort4*)(dst + lane * 4) = oa;
    *(ushort4*)(dst + 256 + lane * 4) = ob;
}

// Fused GEMM(128x256, 8 waves) + mask kernel, 512 threads/block.
// Grid 3072, period-24 interleave: jj<16 -> gemm (2048), else mask (1024).
// 24%8==0 keeps gemm_id&7 == bid&7 (XCD-band property).
// Sim stores are 1KB-contiguous nt runs (restaged through f32[64][256] LDS).
__global__ __launch_bounds__(512, 4) void gemm_mask(
    const unsigned short* __restrict__ Vn, const unsigned short* __restrict__ Tn,
    const int* __restrict__ noisy,
    float* __restrict__ sim_out, float* __restrict__ mask_out,
    float* __restrict__ part)
{
    // 64KB: 2 x (8KB A + 16KB B) staging; epilogue reuses all of it.
    __shared__ __align__(16) unsigned char smem[65536];

    const int bid = blockIdx.x;
    const int grp = bid / 24;
    const int jj  = bid % 24;

    if (jj >= 16) {
        // ---------------- mask path (8 rows/block, 512 threads) ----------------
        const int mask_id = grp * 8 + (jj - 16);     // 0..1023
        const int t = threadIdx.x;
        f32x4 ones;
        ones[0] = ones[1] = ones[2] = ones[3] = 1.0f;
        f32x4 pat[4];
        #pragma unroll
        for (int q = 0; q < 4; ++q) {
            const int4 nz = *(const int4*)&noisy[q * 2048 + t * 4];
            pat[q][0] = nz.x ? 1.0f : 0.0f;
            pat[q][1] = nz.y ? 1.0f : 0.0f;
            pat[q][2] = nz.z ? 1.0f : 0.0f;
            pat[q][3] = nz.w ? 1.0f : 0.0f;
        }
        const int row0 = mask_id * 8;
        for (int r = 0; r < 8; ++r) {
            const int row = row0 + r;
            const int rn = noisy[row];          // uniform per block-row
            float* dst = mask_out + (size_t)row * B_DIM;
            if (rn) {
                #pragma unroll
                for (int q = 0; q < 4; ++q)
                    __builtin_nontemporal_store(ones, (f32x4*)(dst + q * 2048 + t * 4));
            } else {
                #pragma unroll
                for (int q = 0; q < 4; ++q)
                    __builtin_nontemporal_store(pat[q], (f32x4*)(dst + q * 2048 + t * 4));
            }
        }
        return;
    }

    // ---------------- gemm path ----------------
    const int gemm_id = grp * 16 + jj;               // 0..2047

    const int tid  = threadIdx.x;
    const int wave = tid >> 6;      // 0..7
    const int lane = tid & 63;
    const int wr = wave >> 2;       // wave row (0..1), 64 rows each
    const int wc = wave & 3;        // wave col (0..3), 64 cols each

    // XCD-band mapping: xcd = gemm_id&7 owns row band [xcd*8, xcd*8+8) panels
    // of 128 rows; column-panel-major within the band.
    const int xcd = gemm_id & 7;
    const int i   = gemm_id >> 3;      // 0..255
    const int cp  = i >> 3;            // col panel 0..31 (slow)
    const int rp  = i & 7;             // row panel within band (fast)
    const int brow = (xcd * 8 + rp) * BM;
    const int bcol = cp * BN;

    // staging: lane -> (row = lane>>2 within 16-row chunk, chunk = lane&3);
    // source chunk pre-swizzled so LDS(r,c) holds global chunk c^(((r&15)>>1)&3).
    const int sr = lane >> 2;
    const int sc = (((lane & 3) ^ ((lane >> 3) & 3)) * 8);
    const int fr = lane & 15;
    const int ch = ((lane >> 4) ^ ((fr >> 1) & 3)) * 8;

    // buf base (bytes): A at buf*24576 (8KB), B at buf*24576 + 8192 (16KB).
    // Per wave: 1 A-chunk (wave) + 2 B-chunks (wave*2, wave*2+1) => vmcnt 3.
#define STAGE(buf, k0) do {                                                        \
        const unsigned short* ga = Vn + (size_t)(brow + wave * 16 + sr) * D_DIM + (k0) + sc; \
        __builtin_amdgcn_global_load_lds((gas_ptr)ga, (las_ptr)(smem + (buf) * 24576 + wave * 1024), 16, 0, 0); \
        _Pragma("unroll")                                                          \
        for (int q = 0; q < 2; ++q) {                                              \
            const int cw = wave * 2 + q;                                           \
            const unsigned short* gb = Tn + (size_t)(bcol + cw * 16 + sr) * D_DIM + (k0) + sc; \
            __builtin_amdgcn_global_load_lds((gas_ptr)gb, (las_ptr)(smem + (buf) * 24576 + 8192 + cw * 1024), 16, 0, 0); \
        }                                                                          \
    } while (0)

    f32x4 acc[4][4] = {};              // sim^T fragments (4 m x 4 n)

    STAGE(0, 0);                       // tile 0 in flight

    #pragma unroll
    for (int t = 0; t < KSTEPS; ++t) {
        const int cur = t & 1;
        // Only tile t's 3 loads are outstanding (issued one MFMA-phase ago).
        asm volatile("s_waitcnt vmcnt(0)" ::: "memory");
        __builtin_amdgcn_sched_barrier(0);
        __builtin_amdgcn_s_barrier();      // all waves: tile t fully in LDS
        __builtin_amdgcn_sched_barrier(0);

        if (t + 1 < KSTEPS)
            STAGE((t + 1) & 1, (t + 1) * BK);   // in flight across MFMA + next barrier

        const unsigned short* Ab = (const unsigned short*)(smem + cur * 24576);
        const unsigned short* Bb = (const unsigned short*)(smem + cur * 24576 + 8192);
        bf16x8 af[4], bfr[4];
        #pragma unroll
        for (int m = 0; m < 4; ++m)
            af[m] = *(const bf16x8*)&Ab[(wr * 64 + m * 16 + fr) * BK + ch];
        #pragma unroll
        for (int n = 0; n < 4; ++n)
            bfr[n] = *(const bf16x8*)&Bb[(wc * 64 + n * 16 + fr) * BK + ch];

        // swapped operands: lane holds sim[m*16+(lane&15)][n*16+(lane>>4)*4+r]
        // relative to (brow + wr*64, bcol + wc*64)
        #pragma unroll
        for (int m = 0; m < 4; ++m)
            #pragma unroll
            for (int n = 0; n < 4; ++n)
                acc[m][n] = __builtin_amdgcn_mfma_f32_16x16x32_bf16(
                    bfr[n], af[m], acc[m][n], 0, 0, 0);
    }
#undef STAGE

    __syncthreads();   // all waves done reading staging bufs; smem reusable

    const float Tinv = 1.0f / 0.07f;
    const int ci = lane & 15;           // sim row within 16-block
    const int cg = lane >> 4;           // sim col group (4 cols each)

    // ---- rowsum partials (regs -> LDS combine over 4 wc-waves -> 1 store/row) ----
    int rn[4];
    #pragma unroll
    for (int m = 0; m < 4; ++m)
        rn[m] = noisy[brow + wr * 64 + m * 16 + ci];
    int4 cn4[4];
    #pragma unroll
    for (int n = 0; n < 4; ++n)
        cn4[n] = *(const int4*)&noisy[bcol + wc * 64 + n * 16 + cg * 4];

    float* lsum = (float*)smem;        // [4][128] = 2KB
    #pragma unroll
    for (int m = 0; m < 4; ++m) {
        float partial = 0.0f;
        #pragma unroll
        for (int n = 0; n < 4; ++n) {
            const f32x4 s = acc[m][n];
            partial += (rn[m] | cn4[n].x) ? __expf(s[0] * Tinv) : 0.0f;
            partial += (rn[m] | cn4[n].y) ? __expf(s[1] * Tinv) : 0.0f;
            partial += (rn[m] | cn4[n].z) ? __expf(s[2] * Tinv) : 0.0f;
            partial += (rn[m] | cn4[n].w) ? __expf(s[3] * Tinv) : 0.0f;
        }
        partial += __shfl_xor(partial, 16);
        partial += __shfl_xor(partial, 32);
        if (lane < 16) lsum[wc * 128 + wr * 64 + m * 16 + ci] = partial;
    }
    __syncthreads();
    if (tid < 128) {
        const float v = lsum[tid] + lsum[128 + tid] + lsum[256 + tid] + lsum[384 + tid];
        part[(size_t)cp * B_DIM + brow + tid] = v;
    }

    // ---- sim stores: restage through f32[64][256] LDS (64KB), nt 1KB runs ----
    // swizzle: byte ^= (row&15)<<6 (bijective per row; write conflicts hide).
    const int l63  = tid & 63;
    const int w8   = tid >> 6;          // 0..7
    for (int h = 0; h < 2; ++h) {
        __syncthreads();                // lsum reads / prev phase done
        if (wr == h) {                  // 4 waves (wc 0..3) own this row-half
            #pragma unroll
            for (int m = 0; m < 4; ++m) {
                const int row = m * 16 + ci;            // 0..63
                #pragma unroll
                for (int n = 0; n < 4; ++n) {
                    const int col = wc * 64 + n * 16 + cg * 4;   // 0..255
                    int byte = (row * 256 + col) * 4;
                    byte ^= (row & 15) << 6;
                    *(f32x4*)(smem + byte) = acc[m][n];
                }
            }
        }
        __syncthreads();
        #pragma unroll
        for (int j = 0; j < 8; ++j) {
            const int row = j * 8 + w8;                 // 0..63, uniform per wave
            int byte = row * 1024 + l63 * 16;
            byte ^= (row & 15) << 6;
            const f32x4 v = *(const f32x4*)(smem + byte);
            const int grow = brow + h * 64 + row;
            __builtin_nontemporal_store(v,
                (f32x4*)(sim_out + (size_t)grow * B_DIM + bcol + l63 * 4));
        }
    }
}

// stage 1: 32 blocks x 256 rows -> per-block sum of log(rowsum+eps)
__global__ __launch_bounds__(256) void loss_stage1(
    const float* __restrict__ part, float* __restrict__ s1)
{
    __shared__ float wsum[4];
    const int row = blockIdx.x * 256 + threadIdx.x;
    float s = 0.0f;
    #pragma unroll
    for (int c = 0; c < NCP; ++c)
        s += part[(size_t)c * B_DIM + row];
    float l = logf(s + 1e-8f);
    #pragma unroll
    for (int off = 32; off; off >>= 1) l += __shfl_xor(l, off);
    if ((threadIdx.x & 63) == 0) wsum[threadIdx.x >> 6] = l;
    __syncthreads();
    if (threadIdx.x == 0)
        s1[blockIdx.x] = (wsum[0] + wsum[1]) + (wsum[2] + wsum[3]);
}

// stage 2: single wave sums the 32 block partials
__global__ __launch_bounds__(64) void loss_stage2(
    const float* __restrict__ s1, float* __restrict__ out)
{
    const int lane = threadIdx.x;
    float s = (lane < 32) ? s1[lane] : 0.0f;
    #pragma unroll
    for (int off = 32; off; off >>= 1) s += __shfl_xor(s, off);
    if (lane == 0) {
        const float loss = s * (1.0f / (float)B_DIM);
        out[0] = loss;   // complementary_loss
        out[1] = loss;   // brownian_loss (identical chain)
    }
}

extern "C" void kernel_launch(void* const* d_in, const int* in_sizes, int n_in,
                              void* d_out, int out_size, void* d_ws, size_t ws_size,
                              hipStream_t stream) {
    const float* V = (const float*)d_in[0];
    const float* T = (const float*)d_in[1];
    const int* noisy = (const int*)d_in[3];   // confident_clean_mask (d_in[2]) unused
    float* out = (float*)d_out;

    float* mask_out = out + 2;
    float* sim_out  = out + 2 + (size_t)B_DIM * B_DIM;

    unsigned short* Vn = (unsigned short*)d_ws;                       // 8 MB
    unsigned short* Tn = Vn + (size_t)B_DIM * D_DIM;                  // 8 MB
    float* part = (float*)(Tn + (size_t)B_DIM * D_DIM);               // 1 MB
    float* s1   = part + (size_t)NCP * B_DIM;                         // 128 B

    normalize_rows<<<(2 * B_DIM) / 4, 256, 0, stream>>>(V, T, Vn, Tn);
    gemm_mask<<<3072, 512, 0, stream>>>(Vn, Tn, noisy, sim_out, mask_out, part);
    loss_stage1<<<32, 256, 0, stream>>>(part, s1);
    loss_stage2<<<1, 64, 0, stream>>>(s1, out);
}

// Round 14
// 170.290 us; speedup vs baseline: 1.5293x; 1.0126x over previous
//
#include <hip/hip_runtime.h>
#include <hip/hip_bf16.h>
#include <cstdint>

#define B_DIM 8192
#define D_DIM 512
#define BM 128
#define BN 256
#define BK 32
#define KSTEPS (D_DIM / BK)   // 16
#define NCP 32                // col panels (slots in part[])

typedef __attribute__((ext_vector_type(8))) short bf16x8;
typedef __attribute__((ext_vector_type(4))) float f32x4;

typedef __attribute__((address_space(1))) const void* gas_ptr;
typedef __attribute__((address_space(3))) void* las_ptr;

static __device__ __forceinline__ unsigned short f2bf(float x) {
    __hip_bfloat16 h = __float2bfloat16(x);
    return *reinterpret_cast<unsigned short*>(&h);
}

// One wave per row: L2-normalize (f32) and emit bf16.
__global__ __launch_bounds__(256) void normalize_rows(
    const float* __restrict__ V, const float* __restrict__ T,
    unsigned short* __restrict__ Vn, unsigned short* __restrict__ Tn)
{
    const int wave = threadIdx.x >> 6;
    const int lane = threadIdx.x & 63;
    const int row = blockIdx.x * 4 + wave;     // 0..16383 (V rows then T rows)
    const float* src;
    unsigned short* dst;
    if (row < B_DIM) {
        src = V + (size_t)row * D_DIM;
        dst = Vn + (size_t)row * D_DIM;
    } else {
        src = T + (size_t)(row - B_DIM) * D_DIM;
        dst = Tn + (size_t)(row - B_DIM) * D_DIM;
    }
    float4 a = *(const float4*)(src + lane * 4);
    float4 b = *(const float4*)(src + 256 + lane * 4);
    float ss = a.x*a.x + a.y*a.y + a.z*a.z + a.w*a.w
             + b.x*b.x + b.y*b.y + b.z*b.z + b.w*b.w;
    #pragma unroll
    for (int off = 32; off; off >>= 1) ss += __shfl_xor(ss, off);
    const float inv = 1.0f / fmaxf(sqrtf(ss), 1e-12f);
    ushort4 oa, ob;
    oa.x = f2bf(a.x * inv); oa.y = f2bf(a.y * inv);
    oa.z = f2bf(a.z * inv); oa.w = f2bf(a.w * inv);
    ob.x = f2bf(b.x * inv); ob.y = f2bf(b.y * inv);
    ob.z = f2bf(b.z * inv); ob.w = f2bf(b.w * inv);
    *(ushort4*)(dst + lane * 4) = oa;
    *(ushort4*)(dst + 256 + lane * 4) = ob;
}

// Fused GEMM(128x256, 8 waves) + mask kernel, 512 threads/block.
// Grid 3072, period-24 interleave: jj<8 -> mask (1024), else gemm (2048).
// Mask-first: front-loads the sequential store stream into the window where
// early gemm blocks are K-loop-bound (no epilogue stores yet).
// (grp*16)%8==0 keeps gemm_id&7 == bid&7 (XCD-band property).
__global__ __launch_bounds__(512, 4) void gemm_mask(
    const unsigned short* __restrict__ Vn, const unsigned short* __restrict__ Tn,
    const int* __restrict__ noisy,
    float* __restrict__ sim_out, float* __restrict__ mask_out,
    float* __restrict__ part)
{
    // 64KB: 2 x (8KB A + 16KB B) staging; epilogue reuses all of it.
    __shared__ __align__(16) unsigned char smem[65536];

    const int bid = blockIdx.x;
    const int grp = bid / 24;
    const int jj  = bid % 24;

    if (jj < 8) {
        // ---------------- mask path (8 rows/block, 512 threads) ----------------
        const int mask_id = grp * 8 + jj;            // 0..1023
        const int t = threadIdx.x;
        f32x4 ones;
        ones[0] = ones[1] = ones[2] = ones[3] = 1.0f;
        f32x4 pat[4];
        #pragma unroll
        for (int q = 0; q < 4; ++q) {
            const int4 nz = *(const int4*)&noisy[q * 2048 + t * 4];
            pat[q][0] = nz.x ? 1.0f : 0.0f;
            pat[q][1] = nz.y ? 1.0f : 0.0f;
            pat[q][2] = nz.z ? 1.0f : 0.0f;
            pat[q][3] = nz.w ? 1.0f : 0.0f;
        }
        const int row0 = mask_id * 8;
        for (int r = 0; r < 8; ++r) {
            const int row = row0 + r;
            const int rn = noisy[row];          // uniform per block-row
            float* dst = mask_out + (size_t)row * B_DIM;
            if (rn) {
                #pragma unroll
                for (int q = 0; q < 4; ++q)
                    __builtin_nontemporal_store(ones, (f32x4*)(dst + q * 2048 + t * 4));
            } else {
                #pragma unroll
                for (int q = 0; q < 4; ++q)
                    __builtin_nontemporal_store(pat[q], (f32x4*)(dst + q * 2048 + t * 4));
            }
        }
        return;
    }

    // ---------------- gemm path ----------------
    const int gemm_id = grp * 16 + (jj - 8);         // 0..2047

    const int tid  = threadIdx.x;
    const int wave = tid >> 6;      // 0..7
    const int lane = tid & 63;
    const int wr = wave >> 2;       // wave row (0..1), 64 rows each
    const int wc = wave & 3;        // wave col (0..3), 64 cols each

    // XCD-band mapping: xcd = gemm_id&7 owns row band [xcd*8, xcd*8+8) panels
    // of 128 rows; column-panel-major within the band.
    const int xcd = gemm_id & 7;
    const int i   = gemm_id >> 3;      // 0..255
    const int cp  = i >> 3;            // col panel 0..31 (slow)
    const int rp  = i & 7;             // row panel within band (fast)
    const int brow = (xcd * 8 + rp) * BM;
    const int bcol = cp * BN;

    // staging: lane -> (row = lane>>2 within 16-row chunk, chunk = lane&3);
    // source chunk pre-swizzled so LDS(r,c) holds global chunk c^(((r&15)>>1)&3).
    const int sr = lane >> 2;
    const int sc = (((lane & 3) ^ ((lane >> 3) & 3)) * 8);
    const int fr = lane & 15;
    const int ch = ((lane >> 4) ^ ((fr >> 1) & 3)) * 8;

    // buf base (bytes): A at buf*24576 (8KB), B at buf*24576 + 8192 (16KB).
    // Per wave: 1 A-chunk (wave) + 2 B-chunks (wave*2, wave*2+1) => 3 loads.
#define STAGE(buf, k0) do {                                                        \
        const unsigned short* ga = Vn + (size_t)(brow + wave * 16 + sr) * D_DIM + (k0) + sc; \
        __builtin_amdgcn_global_load_lds((gas_ptr)ga, (las_ptr)(smem + (buf) * 24576 + wave * 1024), 16, 0, 0); \
        _Pragma("unroll")                                                          \
        for (int q = 0; q < 2; ++q) {                                              \
            const int cw = wave * 2 + q;                                           \
            const unsigned short* gb = Tn + (size_t)(bcol + cw * 16 + sr) * D_DIM + (k0) + sc; \
            __builtin_amdgcn_global_load_lds((gas_ptr)gb, (las_ptr)(smem + (buf) * 24576 + 8192 + cw * 1024), 16, 0, 0); \
        }                                                                          \
    } while (0)

    f32x4 acc[4][4] = {};              // sim^T fragments (4 m x 4 n)

    STAGE(0, 0);                       // tile 0 in flight

    #pragma unroll
    for (int t = 0; t < KSTEPS; ++t) {
        const int cur = t & 1;
        // Only tile t's 3 loads are outstanding (issued one MFMA-phase ago).
        asm volatile("s_waitcnt vmcnt(0)" ::: "memory");
        __builtin_amdgcn_sched_barrier(0);
        __builtin_amdgcn_s_barrier();      // all waves: tile t fully in LDS
        __builtin_amdgcn_sched_barrier(0);

        if (t + 1 < KSTEPS)
            STAGE((t + 1) & 1, (t + 1) * BK);   // in flight across MFMA + next barrier

        const unsigned short* Ab = (const unsigned short*)(smem + cur * 24576);
        const unsigned short* Bb = (const unsigned short*)(smem + cur * 24576 + 8192);
        bf16x8 af[4], bfr[4];
        #pragma unroll
        for (int m = 0; m < 4; ++m)
            af[m] = *(const bf16x8*)&Ab[(wr * 64 + m * 16 + fr) * BK + ch];
        #pragma unroll
        for (int n = 0; n < 4; ++n)
            bfr[n] = *(const bf16x8*)&Bb[(wc * 64 + n * 16 + fr) * BK + ch];

        // swapped operands: lane holds sim[m*16+(lane&15)][n*16+(lane>>4)*4+r]
        // relative to (brow + wr*64, bcol + wc*64). setprio: gemm waves win
        // issue arbitration vs co-resident mask waves during the MFMA cluster.
        __builtin_amdgcn_s_setprio(1);
        #pragma unroll
        for (int m = 0; m < 4; ++m)
            #pragma unroll
            for (int n = 0; n < 4; ++n)
                acc[m][n] = __builtin_amdgcn_mfma_f32_16x16x32_bf16(
                    bfr[n], af[m], acc[m][n], 0, 0, 0);
        __builtin_amdgcn_s_setprio(0);
    }
#undef STAGE

    __syncthreads();   // all waves done reading staging bufs; smem reusable

    const float Tinv = 1.0f / 0.07f;
    const int ci = lane & 15;           // sim row within 16-block
    const int cg = lane >> 4;           // sim col group (4 cols each)

    // ---- rowsum partials (regs -> LDS combine over 4 wc-waves -> 1 store/row) ----
    int rn[4];
    #pragma unroll
    for (int m = 0; m < 4; ++m)
        rn[m] = noisy[brow + wr * 64 + m * 16 + ci];
    int4 cn4[4];
    #pragma unroll
    for (int n = 0; n < 4; ++n)
        cn4[n] = *(const int4*)&noisy[bcol + wc * 64 + n * 16 + cg * 4];

    float* lsum = (float*)smem;        // [4][128] = 2KB
    #pragma unroll
    for (int m = 0; m < 4; ++m) {
        float partial = 0.0f;
        #pragma unroll
        for (int n = 0; n < 4; ++n) {
            const f32x4 s = acc[m][n];
            partial += (rn[m] | cn4[n].x) ? __expf(s[0] * Tinv) : 0.0f;
            partial += (rn[m] | cn4[n].y) ? __expf(s[1] * Tinv) : 0.0f;
            partial += (rn[m] | cn4[n].z) ? __expf(s[2] * Tinv) : 0.0f;
            partial += (rn[m] | cn4[n].w) ? __expf(s[3] * Tinv) : 0.0f;
        }
        partial += __shfl_xor(partial, 16);
        partial += __shfl_xor(partial, 32);
        if (lane < 16) lsum[wc * 128 + wr * 64 + m * 16 + ci] = partial;
    }
    __syncthreads();
    if (tid < 128) {
        const float v = lsum[tid] + lsum[128 + tid] + lsum[256 + tid] + lsum[384 + tid];
        part[(size_t)cp * B_DIM + brow + tid] = v;
    }

    // ---- sim stores: restage through f32[64][256] LDS (64KB), nt 1KB runs ----
    // swizzle: byte ^= (row&15)<<6 (bijective per row; write conflicts hide).
    const int l63  = tid & 63;
    const int w8   = tid >> 6;          // 0..7
    for (int h = 0; h < 2; ++h) {
        __syncthreads();                // lsum reads / prev phase done
        if (wr == h) {                  // 4 waves (wc 0..3) own this row-half
            #pragma unroll
            for (int m = 0; m < 4; ++m) {
                const int row = m * 16 + ci;            // 0..63
                #pragma unroll
                for (int n = 0; n < 4; ++n) {
                    const int col = wc * 64 + n * 16 + cg * 4;   // 0..255
                    int byte = (row * 256 + col) * 4;
                    byte ^= (row & 15) << 6;
                    *(f32x4*)(smem + byte) = acc[m][n];
                }
            }
        }
        __syncthreads();
        #pragma unroll
        for (int j = 0; j < 8; ++j) {
            const int row = j * 8 + w8;                 // 0..63, uniform per wave
            int byte = row * 1024 + l63 * 16;
            byte ^= (row & 15) << 6;
            const f32x4 v = *(const f32x4*)(smem + byte);
            const int grow = brow + h * 64 + row;
            __builtin_nontemporal_store(v,
                (f32x4*)(sim_out + (size_t)grow * B_DIM + bcol + l63 * 4));
        }
    }
}

// stage 1: 32 blocks x 256 rows -> per-block sum of log(rowsum+eps)
__global__ __launch_bounds__(256) void loss_stage1(
    const float* __restrict__ part, float* __restrict__ s1)
{
    __shared__ float wsum[4];
    const int row = blockIdx.x * 256 + threadIdx.x;
    float s = 0.0f;
    #pragma unroll
    for (int c = 0; c < NCP; ++c)
        s += part[(size_t)c * B_DIM + row];
    float l = logf(s + 1e-8f);
    #pragma unroll
    for (int off = 32; off; off >>= 1) l += __shfl_xor(l, off);
    if ((threadIdx.x & 63) == 0) wsum[threadIdx.x >> 6] = l;
    __syncthreads();
    if (threadIdx.x == 0)
        s1[blockIdx.x] = (wsum[0] + wsum[1]) + (wsum[2] + wsum[3]);
}

// stage 2: single wave sums the 32 block partials
__global__ __launch_bounds__(64) void loss_stage2(
    const float* __restrict__ s1, float* __restrict__ out)
{
    const int lane = threadIdx.x;
    float s = (lane < 32) ? s1[lane] : 0.0f;
    #pragma unroll
    for (int off = 32; off; off >>= 1) s += __shfl_xor(s, off);
    if (lane == 0) {
        const float loss = s * (1.0f / (float)B_DIM);
        out[0] = loss;   // complementary_loss
        out[1] = loss;   // brownian_loss (identical chain)
    }
}

extern "C" void kernel_launch(void* const* d_in, const int* in_sizes, int n_in,
                              void* d_out, int out_size, void* d_ws, size_t ws_size,
                              hipStream_t stream) {
    const float* V = (const float*)d_in[0];
    const float* T = (const float*)d_in[1];
    const int* noisy = (const int*)d_in[3];   // confident_clean_mask (d_in[2]) unused
    float* out = (float*)d_out;

    float* mask_out = out + 2;
    float* sim_out  = out + 2 + (size_t)B_DIM * B_DIM;

    unsigned short* Vn = (unsigned short*)d_ws;                       // 8 MB
    unsigned short* Tn = Vn + (size_t)B_DIM * D_DIM;                  // 8 MB
    float* part = (float*)(Tn + (size_t)B_DIM * D_DIM);               // 1 MB
    float* s1   = part + (size_t)NCP * B_DIM;                         // 128 B

    normalize_rows<<<(2 * B_DIM) / 4, 256, 0, stream>>>(V, T, Vn, Tn);
    gemm_mask<<<3072, 512, 0, stream>>>(Vn, Tn, noisy, sim_out, mask_out, part);
    loss_stage1<<<32, 256, 0, stream>>>(part, s1);
    loss_stage2<<<1, 64, 0, stream>>>(s1, out);
}